// Round 12
// baseline (1531.219 us; speedup 1.0000x reference)
//
#include <hip/hip_runtime.h>
#include <hip/hip_bf16.h>

// Problem dims (fixed)
#define BB 64
#define PP 196
#define ENCD 512
#define ED 1024
#define HD 1024
#define AD 512
#define VD 20000
#define TT 24
#define VPAD 20096
#define HOFF 32768 // h-part offset (shorts) inside axh
#define NSA 4      // adg K-splits

typedef __attribute__((ext_vector_type(8))) short short8;
typedef __attribute__((ext_vector_type(4))) short short4v;
typedef __attribute__((ext_vector_type(4))) float f32x4;
typedef __attribute__((ext_vector_type(8))) _Float16 h16x8;

__device__ __forceinline__ float sigf(float x) { return 1.f / (1.f + __expf(-x)); }

__device__ __forceinline__ unsigned short f2bf(float f) {
    unsigned u = __builtin_bit_cast(unsigned, f);
    u = (u + 0x7FFFu + ((u >> 16) & 1u)) >> 16;
    return (unsigned short)u;
}
__device__ __forceinline__ void split2(float v, unsigned short& h, unsigned short& l) {
    h = f2bf(v);
    float hf = __builtin_bit_cast(float, ((unsigned)h) << 16);
    l = f2bf(v - hf);
}
__device__ __forceinline__ float bf2f(unsigned short u) {
    return __builtin_bit_cast(float, ((unsigned)u) << 16);
}

// ---- split-store helper: one (kc, n-group) of a weight split job ----
__device__ __forceinline__ void split_store(
    const float* __restrict__ W, unsigned short* __restrict__ oh,
    unsigned short* __restrict__ ol, int N, int Npad, int coff,
    int rowoff, int perm, int kc, int n) {
    int src = perm ? ((n & 3) * 1024 + (n >> 2)) : n;
    short8 vh, vl;
    #pragma unroll
    for (int j = 0; j < 8; ++j) {
        float v = (src < N) ? W[(size_t)(rowoff + kc * 8 + j) * N + src] : 0.f;
        unsigned short h, l; split2(v, h, l);
        vh[j] = (short)h; vl[j] = (short)l;
    }
    size_t o = ((size_t)kc * Npad + coff + n) * 8;
    *(short8*)(oh + o) = vh; *(short8*)(ol + o) = vl;
}

// ---- mega prologue kernel (R11-identical) ----
__global__ __launch_bounds__(256) void megasplit_kernel(
    const float* __restrict__ W_enc, unsigned short* __restrict__ wenc_h, unsigned short* __restrict__ wenc_l,
    const float* __restrict__ W_dec, const float* __restrict__ W_fbeta, const float* __restrict__ W_hh,
    unsigned short* __restrict__ wbig_h, unsigned short* __restrict__ wbig_l,
    const float* __restrict__ W_ih,
    unsigned short* __restrict__ wih1_h, unsigned short* __restrict__ wih1_l,
    unsigned short* __restrict__ wih2_h, unsigned short* __restrict__ wih2_l,
    const float* __restrict__ b_ih, const float* __restrict__ b_hh, float* __restrict__ biasp,
    const int* __restrict__ captions, const float* __restrict__ table, float* __restrict__ emb_f) {
    int bid = blockIdx.x, tid = threadIdx.x;
    if (bid < 128) {
        int local = bid, xb = local & 1, kc = local >> 1;
        split_store(W_enc, wenc_h, wenc_l, 512, 512, 0, 0, 0, kc, xb * 256 + tid);
    } else if (bid < 384) {
        int local = bid - 128, xb = local & 1, kc = local >> 1;
        split_store(W_dec, wbig_h, wbig_l, 512, 5120, 0, 0, 0, kc, xb * 256 + tid);
    } else if (bid < 640) {
        int local = bid - 384, xb = local & 1, kc = local >> 1;
        split_store(W_fbeta, wbig_h, wbig_l, 512, 5120, 512, 0, 0, kc, xb * 256 + tid);
    } else if (bid < 2688) {
        int local = bid - 640, xb = local & 15, kc = local >> 4;
        split_store(W_hh, wbig_h, wbig_l, 4096, 5120, 1024, 0, 1, kc, xb * 256 + tid);
    } else if (bid < 4736) {
        int local = bid - 2688, xb = local & 15, kc = local >> 4;
        split_store(W_ih, wih1_h, wih1_l, 4096, 4096, 0, 0, 1, kc, xb * 256 + tid);
    } else if (bid < 5760) {
        int local = bid - 4736, xb = local & 15, kc = local >> 4;
        split_store(W_ih, wih2_h, wih2_l, 4096, 4096, 0, 1024, 1, kc, xb * 256 + tid);
    } else if (bid < 5776) {
        int n = (bid - 5760) * 256 + tid;
        int src = (n & 3) * 1024 + (n >> 2);
        biasp[n] = b_ih[src] + b_hh[src];
    } else {
        int local = bid - 5776;
        int t = local >> 6, b = local & 63;
        int tok = captions[b * 25 + t];
        const float4* src = (const float4*)(table + (size_t)tok * ED);
        float4* dst = (float4*)(emb_f + ((size_t)t * BB + b) * ED);
        dst[tid] = src[tid];
    }
}

// ---- enc -> bf16 copy (context-phase operand) ----
__global__ __launch_bounds__(256) void enc2bf16_kernel(
    const float* __restrict__ enc, unsigned short* __restrict__ encb) {
    size_t idx = ((size_t)blockIdx.x * 256 + threadIdx.x) * 8;
    float4 v0 = *(const float4*)(enc + idx);
    float4 v1 = *(const float4*)(enc + idx + 4);
    short8 o;
    o[0] = (short)f2bf(v0.x); o[1] = (short)f2bf(v0.y);
    o[2] = (short)f2bf(v0.z); o[3] = (short)f2bf(v0.w);
    o[4] = (short)f2bf(v1.x); o[5] = (short)f2bf(v1.y);
    o[6] = (short)f2bf(v1.z); o[7] = (short)f2bf(v1.w);
    *(short8*)(encb + idx) = o;
}

// ---- wfc split (epilogue only) ----
__global__ __launch_bounds__(256) void split_w_kernel(
    const float* __restrict__ W, unsigned short* __restrict__ oh,
    unsigned short* __restrict__ ol, int N, int Npad, int coff,
    int Nlaunch, int rowoff, int perm) {
    int n = blockIdx.x * 256 + threadIdx.x;
    if (n >= Nlaunch) return;
    split_store(W, oh, ol, N, Npad, coff, rowoff, perm, blockIdx.y, n);
}

__global__ __launch_bounds__(512) void mean_kernel(const float* __restrict__ enc,
                                                   float* __restrict__ mf) {
    int b = blockIdx.x; int e = threadIdx.x;
    const float* base = enc + (size_t)b * PP * ENCD + e;
    float s = 0.f;
    #pragma unroll 4
    for (int p = 0; p < PP; ++p) s += base[(size_t)p * ENCD];
    mf[b * ENCD + e] = s * (1.f / PP);
}

__global__ __launch_bounds__(256) void init_hc_kernel(
    const float* __restrict__ mf,
    const float* __restrict__ Wh, const float* __restrict__ bh,
    const float* __restrict__ Wc, const float* __restrict__ bc,
    unsigned short* __restrict__ hc_h, unsigned short* __restrict__ hc_l,
    float* __restrict__ c0) {
    int b = blockIdx.x;
    int isC = blockIdx.y;
    const float* W    = isC ? Wc : Wh;
    const float* bias = isC ? bc : bh;
    __shared__ float smf[ENCD];
    for (int i = threadIdx.x; i < ENCD; i += 256) smf[i] = mf[b * ENCD + i];
    __syncthreads();
    #pragma unroll
    for (int jj = 0; jj < 4; ++jj) {
        int j = threadIdx.x + jj * 256;
        float acc = bias[j];
        for (int k = 0; k < ENCD; ++k) acc += smf[k] * W[(size_t)k * HD + j];
        if (isC) c0[b * HD + j] = acc;
        else {
            unsigned short h, l; split2(acc, h, l);
            size_t o = ((size_t)(j >> 3) * 64 + b) * 8 + (j & 7);
            hc_h[o] = h; hc_l[o] = l;
        }
    }
}

// ---- big MFMA GEMM, A fp32 (in-kernel split), B chunked hi/lo, prefetched.
//      half_out=1 -> C stored as _Float16. ----
__global__ __launch_bounds__(256) void mfma_gemm_bigf(
    const float* __restrict__ Ap,
    const unsigned short* __restrict__ Bh, const unsigned short* __restrict__ Bl,
    const float* __restrict__ bias, float* __restrict__ C,
    int N, int Npad, int K, int Mtiles, int Ntiles, int inner_m, int half_out) {
    __shared__ __align__(16) short lds[32768];
    short* Ahs = lds;
    short* Als = lds + 8192;
    short* Bhs = lds + 16384;
    short* Bls = lds + 24576;
    int tid = threadIdx.x, lane = tid & 63, w = tid >> 6;
    int nwg = Mtiles * Ntiles;
    int orig = blockIdx.x;
    int q = nwg >> 3, r = nwg & 7;
    int xcd = orig & 7;
    int basew = (xcd < r) ? xcd * (q + 1) : r * (q + 1) + (xcd - r) * q;
    int wg = basew + (orig >> 3);
    int mt, nt;
    if (inner_m) { mt = wg % Mtiles; nt = wg / Mtiles; }
    else         { nt = wg % Ntiles; mt = wg / Ntiles; }
    int m0 = mt * 128, n0 = nt * 128;
    int wr = w >> 1, wc = w & 1;
    f32x4 acc[4][4];
    #pragma unroll
    for (int i = 0; i < 4; ++i)
        #pragma unroll
        for (int j = 0; j < 4; ++j) acc[i][j] = (f32x4){0.f, 0.f, 0.f, 0.f};
    int nsteps = K >> 6;
    float4 va[8];
    short8 rb[2][4];
    auto load_step = [&](int s) {
        int k0 = s * 64, kc0 = s * 8;
        #pragma unroll
        for (int it = 0; it < 8; ++it) {
            int idx = it * 256 + tid; int m = idx >> 4, k4 = idx & 15;
            va[it] = *(const float4*)(Ap + (size_t)(m0 + m) * K + k0 + k4 * 4);
        }
        #pragma unroll
        for (int it = 0; it < 4; ++it) {
            int g = w * 4 + it; int kcl = g >> 1; int rb0 = (g & 1) * 64;
            size_t gb = ((size_t)(kc0 + kcl) * Npad + n0 + rb0 + lane) * 8;
            rb[0][it] = *(const short8*)(Bh + gb);
            rb[1][it] = *(const short8*)(Bl + gb);
        }
    };
    load_step(0);
    for (int s = 0; s < nsteps; ++s) {
        __syncthreads();
        #pragma unroll
        for (int it = 0; it < 8; ++it) {
            int idx = it * 256 + tid; int m = idx >> 4, k4 = idx & 15;
            int kc = k4 >> 1, jh = (k4 & 1) * 4;
            float vv[4] = {va[it].x, va[it].y, va[it].z, va[it].w};
            short4v hv, lv;
            #pragma unroll
            for (int qq = 0; qq < 4; ++qq) {
                unsigned short h, l; split2(vv[qq], h, l);
                hv[qq] = (short)h; lv[qq] = (short)l;
            }
            int o = kc * 1024 + ((m ^ kc) << 3) + jh;
            *(short4v*)(Ahs + o) = hv;
            *(short4v*)(Als + o) = lv;
        }
        #pragma unroll
        for (int it = 0; it < 4; ++it) {
            int g = w * 4 + it; int kcl = g >> 1; int rb0 = (g & 1) * 64;
            int o = (kcl * 128 + rb0 + lane) * 8;
            *(short8*)(Bhs + o) = rb[0][it];
            *(short8*)(Bls + o) = rb[1][it];
        }
        __syncthreads();
        if (s + 1 < nsteps) load_step(s + 1);
        #pragma unroll
        for (int ks = 0; ks < 2; ++ks) {
            int kq = ks * 4 + (lane >> 4);
            short8 afh[4], afl[4], bfh[4], bfl[4];
            #pragma unroll
            for (int mi = 0; mi < 4; ++mi) {
                int row = wr * 64 + mi * 16 + (lane & 15);
                int o = kq * 1024 + ((row ^ kq) << 3);
                afh[mi] = *(const short8*)(Ahs + o);
                afl[mi] = *(const short8*)(Als + o);
            }
            #pragma unroll
            for (int ni = 0; ni < 4; ++ni) {
                int o = (kq * 128 + wc * 64 + ni * 16 + (lane & 15)) * 8;
                bfh[ni] = *(const short8*)(Bhs + o);
                bfl[ni] = *(const short8*)(Bls + o);
            }
            #pragma unroll
            for (int mi = 0; mi < 4; ++mi)
                #pragma unroll
                for (int ni = 0; ni < 4; ++ni) {
                    acc[mi][ni] = __builtin_amdgcn_mfma_f32_16x16x32_bf16(afh[mi], bfh[ni], acc[mi][ni], 0, 0, 0);
                    acc[mi][ni] = __builtin_amdgcn_mfma_f32_16x16x32_bf16(afh[mi], bfl[ni], acc[mi][ni], 0, 0, 0);
                    acc[mi][ni] = __builtin_amdgcn_mfma_f32_16x16x32_bf16(afl[mi], bfh[ni], acc[mi][ni], 0, 0, 0);
                }
        }
    }
    #pragma unroll
    for (int mi = 0; mi < 4; ++mi) {
        int rrow = m0 + wr * 64 + mi * 16 + ((lane >> 4) << 2);
        #pragma unroll
        for (int ni = 0; ni < 4; ++ni) {
            int c = n0 + wc * 64 + ni * 16 + (lane & 15);
            if (c < N) {
                float bv = bias ? bias[c] : 0.f;
                if (half_out) {
                    _Float16* Ch = (_Float16*)C;
                    #pragma unroll
                    for (int qq = 0; qq < 4; ++qq)
                        Ch[(size_t)(rrow + qq) * N + c] = (_Float16)(acc[mi][ni][qq] + bv);
                } else {
                    #pragma unroll
                    for (int qq = 0; qq < 4; ++qq)
                        C[(size_t)(rrow + qq) * N + c] = acc[mi][ni][qq] + bv;
                }
            }
        }
    }
}

// ---- phase-1: adg = h @ [W_dec|W_fbeta|Whh(perm)] — zero-barrier, Ksplit=4 ----
__global__ __launch_bounds__(256) void hgemm_direct(
    const unsigned short* __restrict__ Ah, const unsigned short* __restrict__ Al,
    const unsigned short* __restrict__ Bh, const unsigned short* __restrict__ Bl,
    float* __restrict__ out) {
    int tid = threadIdx.x, lane = tid & 63, w = tid >> 6;
    int n0 = blockIdx.x * 128 + w * 32;
    int kc0 = blockIdx.y * 32;
    out += (size_t)blockIdx.y * 64 * 5120;
    f32x4 acc[4][2];
    #pragma unroll
    for (int i = 0; i < 4; ++i)
        #pragma unroll
        for (int j = 0; j < 2; ++j) acc[i][j] = (f32x4){0.f, 0.f, 0.f, 0.f};
    #pragma unroll
    for (int s = 0; s < 8; ++s) {
        int kc = kc0 + s * 4 + (lane >> 4);
        short8 afh[4], afl[4], bfh[2], bfl[2];
        #pragma unroll
        for (int mi = 0; mi < 4; ++mi) {
            size_t o = ((size_t)kc * 64 + mi * 16 + (lane & 15)) * 8;
            afh[mi] = *(const short8*)(Ah + o);
            afl[mi] = *(const short8*)(Al + o);
        }
        #pragma unroll
        for (int ni = 0; ni < 2; ++ni) {
            size_t o = ((size_t)kc * 5120 + n0 + ni * 16 + (lane & 15)) * 8;
            bfh[ni] = *(const short8*)(Bh + o);
            bfl[ni] = *(const short8*)(Bl + o);
        }
        #pragma unroll
        for (int mi = 0; mi < 4; ++mi)
            #pragma unroll
            for (int ni = 0; ni < 2; ++ni) {
                acc[mi][ni] = __builtin_amdgcn_mfma_f32_16x16x32_bf16(afh[mi], bfh[ni], acc[mi][ni], 0, 0, 0);
                acc[mi][ni] = __builtin_amdgcn_mfma_f32_16x16x32_bf16(afh[mi], bfl[ni], acc[mi][ni], 0, 0, 0);
                acc[mi][ni] = __builtin_amdgcn_mfma_f32_16x16x32_bf16(afl[mi], bfh[ni], acc[mi][ni], 0, 0, 0);
            }
    }
    #pragma unroll
    for (int mi = 0; mi < 4; ++mi) {
        int rrow = mi * 16 + ((lane >> 4) << 2);
        #pragma unroll
        for (int ni = 0; ni < 2; ++ni) {
            int c = n0 + ni * 16 + (lane & 15);
            #pragma unroll
            for (int qq = 0; qq < 4; ++qq)
                out[(size_t)(rrow + qq) * 5120 + c] = acc[mi][ni][qq];
        }
    }
}

// ---- fused per-step attention (energy fp16 att_enc; context bf16 enc) ----
__global__ __launch_bounds__(1024) void attn_ctx_kernel(
    const _Float16* __restrict__ att_enc, const float* __restrict__ adg,
    const float* __restrict__ b_dec, const float* __restrict__ Wfull,
    const unsigned short* __restrict__ encb, const float* __restrict__ b_fbeta,
    float* __restrict__ alpha_out, unsigned short* __restrict__ x2h,
    unsigned short* __restrict__ x2l, int t) {
    int b = blockIdx.x; int tid = threadIdx.x;
    __shared__ float sdec[AD], sw[AD], sgate[AD], sal[256], sE[256], red[256];
    __shared__ float sctx[2][AD];
    if (tid < AD) {
        float s = b_dec[tid];
        #pragma unroll
        for (int ks = 0; ks < NSA; ++ks) s += adg[((size_t)ks * BB + b) * 5120 + tid];
        sdec[tid] = s;
        sw[tid] = Wfull[tid];
    } else {
        int e = tid - AD;
        float s = b_fbeta[e];
        #pragma unroll
        for (int ks = 0; ks < NSA; ++ks) s += adg[((size_t)ks * BB + b) * 5120 + 512 + e];
        sgate[e] = s;
    }
    __syncthreads();
    int w = tid >> 6, lane = tid & 63;
    float4 sd0 = *(const float4*)&sdec[lane * 8];
    float4 sd1 = *(const float4*)&sdec[lane * 8 + 4];
    float4 sw0 = *(const float4*)&sw[lane * 8];
    float4 sw1 = *(const float4*)&sw[lane * 8 + 4];
    for (int p = w; p < PP; p += 16) {
        const _Float16* row = att_enc + ((size_t)b * PP + p) * AD + lane * 8;
        h16x8 hv = *(const h16x8*)row;
        float part = fmaxf((float)hv[0] + sd0.x, 0.f) * sw0.x +
                     fmaxf((float)hv[1] + sd0.y, 0.f) * sw0.y +
                     fmaxf((float)hv[2] + sd0.z, 0.f) * sw0.z +
                     fmaxf((float)hv[3] + sd0.w, 0.f) * sw0.w +
                     fmaxf((float)hv[4] + sd1.x, 0.f) * sw1.x +
                     fmaxf((float)hv[5] + sd1.y, 0.f) * sw1.y +
                     fmaxf((float)hv[6] + sd1.z, 0.f) * sw1.z +
                     fmaxf((float)hv[7] + sd1.w, 0.f) * sw1.w;
        #pragma unroll
        for (int off = 32; off > 0; off >>= 1) part += __shfl_down(part, off, 64);
        if (lane == 0) sE[p] = part;
    }
    __syncthreads();
    float myE = (tid < PP) ? sE[tid] : -1e30f;
    if (tid < 256) red[tid] = myE;
    __syncthreads();
    for (int s = 128; s > 0; s >>= 1) {
        if (tid < s) red[tid] = fmaxf(red[tid], red[tid + s]);
        __syncthreads();
    }
    float mx = red[0];
    __syncthreads();
    float ex = (tid < PP) ? __expf(myE - mx) : 0.f;
    if (tid < 256) red[tid] = ex;
    __syncthreads();
    for (int s = 128; s > 0; s >>= 1) {
        if (tid < s) red[tid] += red[tid + s];
        __syncthreads();
    }
    if (tid < PP) {
        float al = ex * (1.f / red[0]);
        sal[tid] = al;
        alpha_out[((size_t)b * TT + t) * PP + tid] = al;
    }
    __syncthreads();
    int e = tid & 511, half = tid >> 9;
    const unsigned short* basep = encb + (size_t)b * PP * ENCD + e;
    float s2 = 0.f;
    #pragma unroll 2
    for (int p = half * 98; p < half * 98 + 98; ++p)
        s2 += sal[p] * bf2f(basep[(size_t)p * ENCD]);
    sctx[half][e] = s2;
    __syncthreads();
    if (tid < AD) {
        float ctx = sctx[0][tid] + sctx[1][tid];
        float gate = sigf(sgate[tid]);
        unsigned short h, l; split2(gate * ctx, h, l);
        size_t o = ((size_t)(tid >> 3) * 64 + b) * 8 + (tid & 7);
        x2h[o] = h; x2l[o] = l;
    }
}

// ---- phase-3: gates = x2 @ Wih2(perm) + pregates + hWhh partials -> LSTM ----
__global__ __launch_bounds__(256) void gates_lstm2(
    const unsigned short* __restrict__ Ah, const unsigned short* __restrict__ Al,
    const unsigned short* __restrict__ Bh, const unsigned short* __restrict__ Bl,
    const float* __restrict__ pregates, const float* __restrict__ adg,
    float* __restrict__ c, unsigned short* __restrict__ ho_h,
    unsigned short* __restrict__ ho_l, float* __restrict__ h_all, int t) {
    __shared__ float gl[4][64][33];
    int tid = threadIdx.x, lane = tid & 63, w = tid >> 6;
    int n0 = blockIdx.x * 32;
    f32x4 acc[4][2];
    #pragma unroll
    for (int i = 0; i < 4; ++i)
        #pragma unroll
        for (int j = 0; j < 2; ++j) acc[i][j] = (f32x4){0.f, 0.f, 0.f, 0.f};
    #pragma unroll
    for (int s = 0; s < 4; ++s) {
        int kc = w * 16 + s * 4 + (lane >> 4);
        short8 afh[4], afl[4], bfh[2], bfl[2];
        #pragma unroll
        for (int mi = 0; mi < 4; ++mi) {
            size_t o = ((size_t)kc * 64 + mi * 16 + (lane & 15)) * 8;
            afh[mi] = *(const short8*)(Ah + o);
            afl[mi] = *(const short8*)(Al + o);
        }
        #pragma unroll
        for (int ni = 0; ni < 2; ++ni) {
            size_t o = ((size_t)kc * 4096 + n0 + ni * 16 + (lane & 15)) * 8;
            bfh[ni] = *(const short8*)(Bh + o);
            bfl[ni] = *(const short8*)(Bl + o);
        }
        #pragma unroll
        for (int mi = 0; mi < 4; ++mi)
            #pragma unroll
            for (int ni = 0; ni < 2; ++ni) {
                acc[mi][ni] = __builtin_amdgcn_mfma_f32_16x16x32_bf16(afh[mi], bfh[ni], acc[mi][ni], 0, 0, 0);
                acc[mi][ni] = __builtin_amdgcn_mfma_f32_16x16x32_bf16(afh[mi], bfl[ni], acc[mi][ni], 0, 0, 0);
                acc[mi][ni] = __builtin_amdgcn_mfma_f32_16x16x32_bf16(afl[mi], bfh[ni], acc[mi][ni], 0, 0, 0);
            }
    }
    #pragma unroll
    for (int mi = 0; mi < 4; ++mi) {
        int rrow = mi * 16 + ((lane >> 4) << 2);
        #pragma unroll
        for (int ni = 0; ni < 2; ++ni) {
            int cl = ni * 16 + (lane & 15);
            #pragma unroll
            for (int qq = 0; qq < 4; ++qq)
                gl[w][rrow + qq][cl] = acc[mi][ni][qq];
        }
    }
    __syncthreads();
    #pragma unroll
    for (int i = 0; i < 2; ++i) {
        int idx = tid + i * 256;
        int b = idx >> 3, jl = idx & 7;
        float g4[4];
        #pragma unroll
        for (int qq = 0; qq < 4; ++qq)
            g4[qq] = gl[0][b][4 * jl + qq] + gl[1][b][4 * jl + qq] +
                     gl[2][b][4 * jl + qq] + gl[3][b][4 * jl + qq];
        {
            float4 pv = *(const float4*)&pregates[((size_t)(t * 64 + b)) * 4096 + n0 + 4 * jl];
            g4[0] += pv.x; g4[1] += pv.y; g4[2] += pv.z; g4[3] += pv.w;
        }
        #pragma unroll
        for (int ks = 0; ks < NSA; ++ks) {
            float4 av = *(const float4*)&adg[((size_t)ks * BB + b) * 5120 + 1024 + n0 + 4 * jl];
            g4[0] += av.x; g4[1] += av.y; g4[2] += av.z; g4[3] += av.w;
        }
        int j = (n0 >> 2) + jl;
        float cn = sigf(g4[1]) * c[b * HD + j] + sigf(g4[0]) * tanhf(g4[2]);
        c[b * HD + j] = cn;
        float hn = sigf(g4[3]) * tanhf(cn);
        unsigned short h, l; split2(hn, h, l);
        size_t o1 = ((size_t)(j >> 3) * 64 + b) * 8 + (j & 7);
        ho_h[o1] = h; ho_l[o1] = l;
        h_all[((size_t)b * TT + t) * HD + j] = hn;
    }
}

extern "C" void kernel_launch(void* const* d_in, const int* in_sizes, int n_in,
                              void* d_out, int out_size, void* d_ws, size_t ws_size,
                              hipStream_t stream) {
    const float* enc      = (const float*)d_in[0];
    const int*   captions = (const int*)d_in[1];
    const float* W_enc    = (const float*)d_in[3];
    const float* b_enc    = (const float*)d_in[4];
    const float* W_dec    = (const float*)d_in[5];
    const float* b_dec    = (const float*)d_in[6];
    const float* W_full   = (const float*)d_in[7];
    const float* table    = (const float*)d_in[9];
    const float* W_ih     = (const float*)d_in[10];   // [1536][4096]
    const float* b_ih     = (const float*)d_in[11];
    const float* W_hh     = (const float*)d_in[12];   // [1024][4096]
    const float* b_hh     = (const float*)d_in[13];
    const float* W_init_h = (const float*)d_in[14];
    const float* b_init_h = (const float*)d_in[15];
    const float* W_init_c = (const float*)d_in[16];
    const float* b_init_c = (const float*)d_in[17];
    const float* W_fbeta  = (const float*)d_in[18];
    const float* b_fbeta  = (const float*)d_in[19];
    const float* W_fc     = (const float*)d_in[20];
    const float* b_fc     = (const float*)d_in[21];

    float* preds  = (float*)d_out;                         // [64][24][20000]
    float* alphas = (float*)d_out + (size_t)BB * TT * VD;  // [64][24][196]

    // ---- workspace carve (~110 MB). Front region dead after loop -> wfc overlays.
    //      encb aliases wih1 (dead after pregates GEMM). emb_f/adg share scratch0. ----
    char* base = (char*)d_ws;
    size_t off = 0;
    auto take = [&](size_t b) { void* r = (void*)(base + off); off += (b + 255) & ~(size_t)255; return r; };
    _Float16* att_enc = (_Float16*)take((size_t)12544 * 512 * 2);                // 12.9 MB (fp16)
    unsigned short* wbig_h = (unsigned short*)take((size_t)128 * 5120 * 8 * 2);  // 10.5 x2
    unsigned short* wbig_l = (unsigned short*)take((size_t)128 * 5120 * 8 * 2);
    unsigned short* wih1_h = (unsigned short*)take((size_t)128 * 4096 * 8 * 2);  // 8.4 x2
    unsigned short* wih1_l = (unsigned short*)take((size_t)128 * 4096 * 8 * 2);
    unsigned short* encb   = (unsigned short*)wih1_h;   // 12.85 MB <= 16.8 MB, written after pregates GEMM
    unsigned short* wih2_h = (unsigned short*)take((size_t)64 * 4096 * 8 * 2);   // 4.2 x2
    unsigned short* wih2_l = (unsigned short*)take((size_t)64 * 4096 * 8 * 2);
    unsigned short* wenc_h = (unsigned short*)take((size_t)64 * 512 * 8 * 2);    // 0.52 x2
    unsigned short* wenc_l = (unsigned short*)take((size_t)64 * 512 * 8 * 2);
    float* pregates = (float*)take((size_t)TT * BB * 4096 * 4);                  // 25.2
    float* scratch0 = (float*)take((size_t)TT * BB * ED * 4);                    // 6.3 (emb_f / adg union)
    float* emb_f    = scratch0;
    float* adg      = scratch0;   // NSA*64*5120*4 = 5.24 MB <= 6.3 MB
    float* biasp    = (float*)take((size_t)4096 * 4);
    // wfc overlays [0, off): written AFTER the loop
    unsigned short* wfc_h = (unsigned short*)(base);
    unsigned short* wfc_l = (unsigned short*)(base + (size_t)128 * VPAD * 8 * 2);
    // persistent (live across wfc write):
    float* c_buf = (float*)take((size_t)BB * HD * 4);
    float* mf    = (float*)take((size_t)BB * ENCD * 4);
    unsigned short* axh_h0 = (unsigned short*)take((size_t)192 * 64 * 8 * 2);
    unsigned short* axh_l0 = (unsigned short*)take((size_t)192 * 64 * 8 * 2);
    unsigned short* axh_h1 = (unsigned short*)take((size_t)192 * 64 * 8 * 2);
    unsigned short* axh_l1 = (unsigned short*)take((size_t)192 * 64 * 8 * 2);
    float* h_all = (float*)take((size_t)TT * BB * HD * 4);                       // 6.3

    // ---- prologue ----
    megasplit_kernel<<<7312, 256, 0, stream>>>(
        W_enc, wenc_h, wenc_l, W_dec, W_fbeta, W_hh, wbig_h, wbig_l,
        W_ih, wih1_h, wih1_l, wih2_h, wih2_l,
        b_ih, b_hh, biasp, captions, table, emb_f);
    mean_kernel<<<BB, 512, 0, stream>>>(enc, mf);
    init_hc_kernel<<<dim3(BB, 2), 256, 0, stream>>>(mf, W_init_h, b_init_h, W_init_c, b_init_c,
                                                    axh_h0 + HOFF, axh_l0 + HOFF, c_buf);
    // att_enc(fp16) = enc @ W_enc + b_enc : M=12544 N=512 K=512
    mfma_gemm_bigf<<<392, 256, 0, stream>>>(enc, wenc_h, wenc_l, b_enc, (float*)att_enc,
                                            512, 512, 512, 98, 4, 0, 1);
    // pregates = emb @ W_ih[0:1024] (perm cols) + (b_ih+b_hh) perm : M=1536 N=4096 K=1024
    mfma_gemm_bigf<<<384, 256, 0, stream>>>(emb_f, wih1_h, wih1_l, biasp, pregates,
                                            4096, 4096, 1024, 12, 32, 1, 0);
    // enc -> bf16 (context operand); aliases wih1 which is now dead
    enc2bf16_kernel<<<3136, 256, 0, stream>>>(enc, encb);

    // ---- step loop: 3 dispatches/step ----
    {
        unsigned short* ah[2] = {axh_h0, axh_h1};
        unsigned short* al[2] = {axh_l0, axh_l1};
        for (int t = 0; t < TT; ++t) {
            int par = t & 1;
            hgemm_direct<<<dim3(40, NSA), 256, 0, stream>>>(
                ah[par] + HOFF, al[par] + HOFF, wbig_h, wbig_l, adg);
            attn_ctx_kernel<<<BB, 1024, 0, stream>>>(att_enc, adg, b_dec, W_full, encb,
                                                     b_fbeta, alphas, ah[par], al[par], t);
            gates_lstm2<<<128, 256, 0, stream>>>(
                ah[par], al[par], wih2_h, wih2_l, pregates, adg, c_buf,
                ah[1 - par] + HOFF, al[1 - par] + HOFF, h_all, t);
        }
    }

    // ---- epilogue ----
    split_w_kernel<<<dim3(79, 128), 256, 0, stream>>>(W_fc, wfc_h, wfc_l, VD, VPAD, 0, VPAD, 0, 0);
    mfma_gemm_bigf<<<1884, 256, 0, stream>>>(h_all, wfc_h, wfc_l, b_fc, preds,
                                             VD, VPAD, 1024, 12, 157, 1, 0);
}

// Round 13
// 1512.313 us; speedup vs baseline: 1.0125x; 1.0125x over previous
//
#include <hip/hip_runtime.h>
#include <hip/hip_bf16.h>

// Problem dims (fixed)
#define BB 64
#define PP 196
#define ENCD 512
#define ED 1024
#define HD 1024
#define AD 512
#define VD 20000
#define TT 24
#define VPAD 20096
#define HOFF 32768 // h-part offset (shorts) inside axh
#define NSA 4      // adg K-splits

typedef __attribute__((ext_vector_type(8))) short short8;
typedef __attribute__((ext_vector_type(4))) short short4v;
typedef __attribute__((ext_vector_type(4))) float f32x4;
typedef __attribute__((ext_vector_type(8))) _Float16 h16x8;

__device__ __forceinline__ float sigf(float x) { return 1.f / (1.f + __expf(-x)); }

__device__ __forceinline__ unsigned short f2bf(float f) {
    unsigned u = __builtin_bit_cast(unsigned, f);
    u = (u + 0x7FFFu + ((u >> 16) & 1u)) >> 16;
    return (unsigned short)u;
}
__device__ __forceinline__ void split2(float v, unsigned short& h, unsigned short& l) {
    h = f2bf(v);
    float hf = __builtin_bit_cast(float, ((unsigned)h) << 16);
    l = f2bf(v - hf);
}
__device__ __forceinline__ float bf2f(unsigned short u) {
    return __builtin_bit_cast(float, ((unsigned)u) << 16);
}

// ---- split-store helper: one (kc, n-group) of a weight split job ----
__device__ __forceinline__ void split_store(
    const float* __restrict__ W, unsigned short* __restrict__ oh,
    unsigned short* __restrict__ ol, int N, int Npad, int coff,
    int rowoff, int perm, int kc, int n) {
    int src = perm ? ((n & 3) * 1024 + (n >> 2)) : n;
    short8 vh, vl;
    #pragma unroll
    for (int j = 0; j < 8; ++j) {
        float v = (src < N) ? W[(size_t)(rowoff + kc * 8 + j) * N + src] : 0.f;
        unsigned short h, l; split2(v, h, l);
        vh[j] = (short)h; vl[j] = (short)l;
    }
    size_t o = ((size_t)kc * Npad + coff + n) * 8;
    *(short8*)(oh + o) = vh; *(short8*)(ol + o) = vl;
}

// ---- mega prologue kernel: weight splits + bias_perm + embed gather-split ----
__global__ __launch_bounds__(256) void megasplit_kernel(
    const float* __restrict__ W_enc, unsigned short* __restrict__ wenc_h, unsigned short* __restrict__ wenc_l,
    const float* __restrict__ W_dec, const float* __restrict__ W_fbeta, const float* __restrict__ W_hh,
    unsigned short* __restrict__ wbig_h, unsigned short* __restrict__ wbig_l,
    const float* __restrict__ W_ih,
    unsigned short* __restrict__ wih1_h, unsigned short* __restrict__ wih1_l,
    unsigned short* __restrict__ wih2_h, unsigned short* __restrict__ wih2_l,
    const float* __restrict__ b_ih, const float* __restrict__ b_hh, float* __restrict__ biasp,
    const int* __restrict__ captions, const float* __restrict__ table,
    unsigned short* __restrict__ embc_h, unsigned short* __restrict__ embc_l) {
    int bid = blockIdx.x, tid = threadIdx.x;
    if (bid < 128) {
        int local = bid, xb = local & 1, kc = local >> 1;
        split_store(W_enc, wenc_h, wenc_l, 512, 512, 0, 0, 0, kc, xb * 256 + tid);
    } else if (bid < 384) {
        int local = bid - 128, xb = local & 1, kc = local >> 1;
        split_store(W_dec, wbig_h, wbig_l, 512, 5120, 0, 0, 0, kc, xb * 256 + tid);
    } else if (bid < 640) {
        int local = bid - 384, xb = local & 1, kc = local >> 1;
        split_store(W_fbeta, wbig_h, wbig_l, 512, 5120, 512, 0, 0, kc, xb * 256 + tid);
    } else if (bid < 2688) {
        int local = bid - 640, xb = local & 15, kc = local >> 4;
        split_store(W_hh, wbig_h, wbig_l, 4096, 5120, 1024, 0, 1, kc, xb * 256 + tid);
    } else if (bid < 4736) {
        int local = bid - 2688, xb = local & 15, kc = local >> 4;
        split_store(W_ih, wih1_h, wih1_l, 4096, 4096, 0, 0, 1, kc, xb * 256 + tid);
    } else if (bid < 5760) {
        int local = bid - 4736, xb = local & 15, kc = local >> 4;
        split_store(W_ih, wih2_h, wih2_l, 4096, 4096, 0, 1024, 1, kc, xb * 256 + tid);
    } else if (bid < 5776) {
        int n = (bid - 5760) * 256 + tid;
        int src = (n & 3) * 1024 + (n >> 2);
        biasp[n] = b_ih[src] + b_hh[src];
    } else {
        // embed gather + split -> chunked [kc][t*64+b][8] hi/lo
        int local = bid - 5776;
        int t = local >> 6, b = local & 63;
        if (tid < 128) {
            int kc = tid;
            int tok = captions[b * 25 + t];
            const float* row = table + (size_t)tok * ED + kc * 8;
            short8 vh, vl;
            #pragma unroll
            for (int j = 0; j < 8; ++j) {
                unsigned short h, l; split2(row[j], h, l);
                vh[j] = (short)h; vl[j] = (short)l;
            }
            size_t o = ((size_t)kc * (TT * BB) + t * BB + b) * 8;
            *(short8*)(embc_h + o) = vh; *(short8*)(embc_l + o) = vl;
        }
    }
}

// ---- enc -> bf16 copy (context-phase operand) ----
__global__ __launch_bounds__(256) void enc2bf16_kernel(
    const float* __restrict__ enc, unsigned short* __restrict__ encb) {
    size_t idx = ((size_t)blockIdx.x * 256 + threadIdx.x) * 8;
    float4 v0 = *(const float4*)(enc + idx);
    float4 v1 = *(const float4*)(enc + idx + 4);
    short8 o;
    o[0] = (short)f2bf(v0.x); o[1] = (short)f2bf(v0.y);
    o[2] = (short)f2bf(v0.z); o[3] = (short)f2bf(v0.w);
    o[4] = (short)f2bf(v1.x); o[5] = (short)f2bf(v1.y);
    o[6] = (short)f2bf(v1.z); o[7] = (short)f2bf(v1.w);
    *(short8*)(encb + idx) = o;
}

// ---- wfc split (epilogue only) ----
__global__ __launch_bounds__(256) void split_w_kernel(
    const float* __restrict__ W, unsigned short* __restrict__ oh,
    unsigned short* __restrict__ ol, int N, int Npad, int coff,
    int Nlaunch, int rowoff, int perm) {
    int n = blockIdx.x * 256 + threadIdx.x;
    if (n >= Nlaunch) return;
    split_store(W, oh, ol, N, Npad, coff, rowoff, perm, blockIdx.y, n);
}

__global__ __launch_bounds__(512) void mean_kernel(const float* __restrict__ enc,
                                                   float* __restrict__ mf) {
    int b = blockIdx.x; int e = threadIdx.x;
    const float* base = enc + (size_t)b * PP * ENCD + e;
    float s = 0.f;
    #pragma unroll 4
    for (int p = 0; p < PP; ++p) s += base[(size_t)p * ENCD];
    mf[b * ENCD + e] = s * (1.f / PP);
}

__global__ __launch_bounds__(256) void init_hc_kernel(
    const float* __restrict__ mf,
    const float* __restrict__ Wh, const float* __restrict__ bh,
    const float* __restrict__ Wc, const float* __restrict__ bc,
    unsigned short* __restrict__ hc_h, unsigned short* __restrict__ hc_l,
    float* __restrict__ c0) {
    int b = blockIdx.x;
    int isC = blockIdx.y;
    const float* W    = isC ? Wc : Wh;
    const float* bias = isC ? bc : bh;
    __shared__ float smf[ENCD];
    for (int i = threadIdx.x; i < ENCD; i += 256) smf[i] = mf[b * ENCD + i];
    __syncthreads();
    #pragma unroll
    for (int jj = 0; jj < 4; ++jj) {
        int j = threadIdx.x + jj * 256;
        float acc = bias[j];
        for (int k = 0; k < ENCD; ++k) acc += smf[k] * W[(size_t)k * HD + j];
        if (isC) c0[b * HD + j] = acc;
        else {
            unsigned short h, l; split2(acc, h, l);
            size_t o = ((size_t)(j >> 3) * 64 + b) * 8 + (j & 7);
            hc_h[o] = h; hc_l[o] = l;
        }
    }
}

// ---- big MFMA GEMM, A fp32 (in-kernel split) — used for att_enc only ----
__global__ __launch_bounds__(256) void mfma_gemm_bigf(
    const float* __restrict__ Ap,
    const unsigned short* __restrict__ Bh, const unsigned short* __restrict__ Bl,
    const float* __restrict__ bias, float* __restrict__ C,
    int N, int Npad, int K, int Mtiles, int Ntiles, int inner_m, int half_out) {
    __shared__ __align__(16) short lds[32768];
    short* Ahs = lds;
    short* Als = lds + 8192;
    short* Bhs = lds + 16384;
    short* Bls = lds + 24576;
    int tid = threadIdx.x, lane = tid & 63, w = tid >> 6;
    int nwg = Mtiles * Ntiles;
    int orig = blockIdx.x;
    int q = nwg >> 3, r = nwg & 7;
    int xcd = orig & 7;
    int basew = (xcd < r) ? xcd * (q + 1) : r * (q + 1) + (xcd - r) * q;
    int wg = basew + (orig >> 3);
    int mt, nt;
    if (inner_m) { mt = wg % Mtiles; nt = wg / Mtiles; }
    else         { nt = wg % Ntiles; mt = wg / Ntiles; }
    int m0 = mt * 128, n0 = nt * 128;
    int wr = w >> 1, wc = w & 1;
    f32x4 acc[4][4];
    #pragma unroll
    for (int i = 0; i < 4; ++i)
        #pragma unroll
        for (int j = 0; j < 4; ++j) acc[i][j] = (f32x4){0.f, 0.f, 0.f, 0.f};
    int nsteps = K >> 6;
    float4 va[8];
    short8 rb[2][4];
    auto load_step = [&](int s) {
        int k0 = s * 64, kc0 = s * 8;
        #pragma unroll
        for (int it = 0; it < 8; ++it) {
            int idx = it * 256 + tid; int m = idx >> 4, k4 = idx & 15;
            va[it] = *(const float4*)(Ap + (size_t)(m0 + m) * K + k0 + k4 * 4);
        }
        #pragma unroll
        for (int it = 0; it < 4; ++it) {
            int g = w * 4 + it; int kcl = g >> 1; int rb0 = (g & 1) * 64;
            size_t gb = ((size_t)(kc0 + kcl) * Npad + n0 + rb0 + lane) * 8;
            rb[0][it] = *(const short8*)(Bh + gb);
            rb[1][it] = *(const short8*)(Bl + gb);
        }
    };
    load_step(0);
    for (int s = 0; s < nsteps; ++s) {
        __syncthreads();
        #pragma unroll
        for (int it = 0; it < 8; ++it) {
            int idx = it * 256 + tid; int m = idx >> 4, k4 = idx & 15;
            int kc = k4 >> 1, jh = (k4 & 1) * 4;
            float vv[4] = {va[it].x, va[it].y, va[it].z, va[it].w};
            short4v hv, lv;
            #pragma unroll
            for (int qq = 0; qq < 4; ++qq) {
                unsigned short h, l; split2(vv[qq], h, l);
                hv[qq] = (short)h; lv[qq] = (short)l;
            }
            int o = kc * 1024 + ((m ^ kc) << 3) + jh;
            *(short4v*)(Ahs + o) = hv;
            *(short4v*)(Als + o) = lv;
        }
        #pragma unroll
        for (int it = 0; it < 4; ++it) {
            int g = w * 4 + it; int kcl = g >> 1; int rb0 = (g & 1) * 64;
            int o = (kcl * 128 + rb0 + lane) * 8;
            *(short8*)(Bhs + o) = rb[0][it];
            *(short8*)(Bls + o) = rb[1][it];
        }
        __syncthreads();
        if (s + 1 < nsteps) load_step(s + 1);
        #pragma unroll
        for (int ks = 0; ks < 2; ++ks) {
            int kq = ks * 4 + (lane >> 4);
            short8 afh[4], afl[4], bfh[4], bfl[4];
            #pragma unroll
            for (int mi = 0; mi < 4; ++mi) {
                int row = wr * 64 + mi * 16 + (lane & 15);
                int o = kq * 1024 + ((row ^ kq) << 3);
                afh[mi] = *(const short8*)(Ahs + o);
                afl[mi] = *(const short8*)(Als + o);
            }
            #pragma unroll
            for (int ni = 0; ni < 4; ++ni) {
                int o = (kq * 128 + wc * 64 + ni * 16 + (lane & 15)) * 8;
                bfh[ni] = *(const short8*)(Bhs + o);
                bfl[ni] = *(const short8*)(Bls + o);
            }
            #pragma unroll
            for (int mi = 0; mi < 4; ++mi)
                #pragma unroll
                for (int ni = 0; ni < 4; ++ni) {
                    acc[mi][ni] = __builtin_amdgcn_mfma_f32_16x16x32_bf16(afh[mi], bfh[ni], acc[mi][ni], 0, 0, 0);
                    acc[mi][ni] = __builtin_amdgcn_mfma_f32_16x16x32_bf16(afh[mi], bfl[ni], acc[mi][ni], 0, 0, 0);
                    acc[mi][ni] = __builtin_amdgcn_mfma_f32_16x16x32_bf16(afl[mi], bfh[ni], acc[mi][ni], 0, 0, 0);
                }
        }
    }
    #pragma unroll
    for (int mi = 0; mi < 4; ++mi) {
        int rrow = m0 + wr * 64 + mi * 16 + ((lane >> 4) << 2);
        #pragma unroll
        for (int ni = 0; ni < 4; ++ni) {
            int c = n0 + wc * 64 + ni * 16 + (lane & 15);
            if (c < N) {
                float bv = bias ? bias[c] : 0.f;
                if (half_out) {
                    _Float16* Ch = (_Float16*)C;
                    #pragma unroll
                    for (int qq = 0; qq < 4; ++qq)
                        Ch[(size_t)(rrow + qq) * N + c] = (_Float16)(acc[mi][ni][qq] + bv);
                } else {
                    #pragma unroll
                    for (int qq = 0; qq < 4; ++qq)
                        C[(size_t)(rrow + qq) * N + c] = acc[mi][ni][qq] + bv;
                }
            }
        }
    }
}

// ---- big MFMA GEMM, A pre-split chunked [kc][Mtot][8] hi/lo — pregates & final ----
__global__ __launch_bounds__(256) void mfma_gemm_bigp(
    const unsigned short* __restrict__ Ah, const unsigned short* __restrict__ Al,
    const unsigned short* __restrict__ Bh, const unsigned short* __restrict__ Bl,
    const float* __restrict__ bias, float* __restrict__ C,
    int Mtot, int N, int Npad, int K, int Mtiles, int Ntiles, int inner_m) {
    __shared__ __align__(16) short lds[32768];
    short* Ahs = lds;          // [8][128][8] linear
    short* Als = lds + 8192;
    short* Bhs = lds + 16384;  // [8][128][8] linear
    short* Bls = lds + 24576;
    int tid = threadIdx.x, lane = tid & 63, w = tid >> 6;
    int nwg = Mtiles * Ntiles;
    int orig = blockIdx.x;
    int q = nwg >> 3, r = nwg & 7;
    int xcd = orig & 7;
    int basew = (xcd < r) ? xcd * (q + 1) : r * (q + 1) + (xcd - r) * q;
    int wg = basew + (orig >> 3);
    int mt, nt;
    if (inner_m) { mt = wg % Mtiles; nt = wg / Mtiles; }
    else         { nt = wg % Ntiles; mt = wg / Ntiles; }
    int m0 = mt * 128, n0 = nt * 128;
    int wr = w >> 1, wc = w & 1;
    f32x4 acc[4][4];
    #pragma unroll
    for (int i = 0; i < 4; ++i)
        #pragma unroll
        for (int j = 0; j < 4; ++j) acc[i][j] = (f32x4){0.f, 0.f, 0.f, 0.f};
    int nsteps = K >> 6;
    short8 ra[2][4], rb[2][4];
    auto load_step = [&](int s) {
        int kc0 = s * 8;
        #pragma unroll
        for (int it = 0; it < 4; ++it) {
            int idx = it * 256 + tid; int kcl = idx >> 7, row = idx & 127;
            size_t ga = ((size_t)(kc0 + kcl) * Mtot + m0 + row) * 8;
            ra[0][it] = *(const short8*)(Ah + ga);
            ra[1][it] = *(const short8*)(Al + ga);
        }
        #pragma unroll
        for (int it = 0; it < 4; ++it) {
            int g = w * 4 + it; int kcl = g >> 1; int rb0 = (g & 1) * 64;
            size_t gb = ((size_t)(kc0 + kcl) * Npad + n0 + rb0 + lane) * 8;
            rb[0][it] = *(const short8*)(Bh + gb);
            rb[1][it] = *(const short8*)(Bl + gb);
        }
    };
    load_step(0);
    for (int s = 0; s < nsteps; ++s) {
        __syncthreads();
        #pragma unroll
        for (int it = 0; it < 4; ++it) {
            int idx = it * 256 + tid; int kcl = idx >> 7, row = idx & 127;
            int o = (kcl * 128 + row) * 8;
            *(short8*)(Ahs + o) = ra[0][it];
            *(short8*)(Als + o) = ra[1][it];
        }
        #pragma unroll
        for (int it = 0; it < 4; ++it) {
            int g = w * 4 + it; int kcl = g >> 1; int rb0 = (g & 1) * 64;
            int o = (kcl * 128 + rb0 + lane) * 8;
            *(short8*)(Bhs + o) = rb[0][it];
            *(short8*)(Bls + o) = rb[1][it];
        }
        __syncthreads();
        if (s + 1 < nsteps) load_step(s + 1);
        #pragma unroll
        for (int ks = 0; ks < 2; ++ks) {
            int kq = ks * 4 + (lane >> 4);
            short8 afh[4], afl[4], bfh[4], bfl[4];
            #pragma unroll
            for (int mi = 0; mi < 4; ++mi) {
                int o = (kq * 128 + wr * 64 + mi * 16 + (lane & 15)) * 8;
                afh[mi] = *(const short8*)(Ahs + o);
                afl[mi] = *(const short8*)(Als + o);
            }
            #pragma unroll
            for (int ni = 0; ni < 4; ++ni) {
                int o = (kq * 128 + wc * 64 + ni * 16 + (lane & 15)) * 8;
                bfh[ni] = *(const short8*)(Bhs + o);
                bfl[ni] = *(const short8*)(Bls + o);
            }
            #pragma unroll
            for (int mi = 0; mi < 4; ++mi)
                #pragma unroll
                for (int ni = 0; ni < 4; ++ni) {
                    acc[mi][ni] = __builtin_amdgcn_mfma_f32_16x16x32_bf16(afh[mi], bfh[ni], acc[mi][ni], 0, 0, 0);
                    acc[mi][ni] = __builtin_amdgcn_mfma_f32_16x16x32_bf16(afh[mi], bfl[ni], acc[mi][ni], 0, 0, 0);
                    acc[mi][ni] = __builtin_amdgcn_mfma_f32_16x16x32_bf16(afl[mi], bfh[ni], acc[mi][ni], 0, 0, 0);
                }
        }
    }
    #pragma unroll
    for (int mi = 0; mi < 4; ++mi) {
        int rrow = m0 + wr * 64 + mi * 16 + ((lane >> 4) << 2);
        #pragma unroll
        for (int ni = 0; ni < 4; ++ni) {
            int c = n0 + wc * 64 + ni * 16 + (lane & 15);
            if (c < N) {
                float bv = bias ? bias[c] : 0.f;
                #pragma unroll
                for (int qq = 0; qq < 4; ++qq)
                    C[(size_t)(rrow + qq) * N + c] = acc[mi][ni][qq] + bv;
            }
        }
    }
}

// ---- phase-1: adg = h @ [W_dec|W_fbeta|Whh(perm)] — zero-barrier, Ksplit=4 ----
__global__ __launch_bounds__(256) void hgemm_direct(
    const unsigned short* __restrict__ Ah, const unsigned short* __restrict__ Al,
    const unsigned short* __restrict__ Bh, const unsigned short* __restrict__ Bl,
    float* __restrict__ out) {
    int tid = threadIdx.x, lane = tid & 63, w = tid >> 6;
    int n0 = blockIdx.x * 128 + w * 32;
    int kc0 = blockIdx.y * 32;
    out += (size_t)blockIdx.y * 64 * 5120;
    f32x4 acc[4][2];
    #pragma unroll
    for (int i = 0; i < 4; ++i)
        #pragma unroll
        for (int j = 0; j < 2; ++j) acc[i][j] = (f32x4){0.f, 0.f, 0.f, 0.f};
    #pragma unroll
    for (int s = 0; s < 8; ++s) {
        int kc = kc0 + s * 4 + (lane >> 4);
        short8 afh[4], afl[4], bfh[2], bfl[2];
        #pragma unroll
        for (int mi = 0; mi < 4; ++mi) {
            size_t o = ((size_t)kc * 64 + mi * 16 + (lane & 15)) * 8;
            afh[mi] = *(const short8*)(Ah + o);
            afl[mi] = *(const short8*)(Al + o);
        }
        #pragma unroll
        for (int ni = 0; ni < 2; ++ni) {
            size_t o = ((size_t)kc * 5120 + n0 + ni * 16 + (lane & 15)) * 8;
            bfh[ni] = *(const short8*)(Bh + o);
            bfl[ni] = *(const short8*)(Bl + o);
        }
        #pragma unroll
        for (int mi = 0; mi < 4; ++mi)
            #pragma unroll
            for (int ni = 0; ni < 2; ++ni) {
                acc[mi][ni] = __builtin_amdgcn_mfma_f32_16x16x32_bf16(afh[mi], bfh[ni], acc[mi][ni], 0, 0, 0);
                acc[mi][ni] = __builtin_amdgcn_mfma_f32_16x16x32_bf16(afh[mi], bfl[ni], acc[mi][ni], 0, 0, 0);
                acc[mi][ni] = __builtin_amdgcn_mfma_f32_16x16x32_bf16(afl[mi], bfh[ni], acc[mi][ni], 0, 0, 0);
            }
    }
    #pragma unroll
    for (int mi = 0; mi < 4; ++mi) {
        int rrow = mi * 16 + ((lane >> 4) << 2);
        #pragma unroll
        for (int ni = 0; ni < 2; ++ni) {
            int c = n0 + ni * 16 + (lane & 15);
            #pragma unroll
            for (int qq = 0; qq < 4; ++qq)
                out[(size_t)(rrow + qq) * 5120 + c] = acc[mi][ni][qq];
        }
    }
}

// ---- fused per-step attention (energy fp16 att_enc; context bf16 enc) ----
__global__ __launch_bounds__(1024) void attn_ctx_kernel(
    const _Float16* __restrict__ att_enc, const float* __restrict__ adg,
    const float* __restrict__ b_dec, const float* __restrict__ Wfull,
    const unsigned short* __restrict__ encb, const float* __restrict__ b_fbeta,
    float* __restrict__ alpha_out, unsigned short* __restrict__ x2h,
    unsigned short* __restrict__ x2l, int t) {
    int b = blockIdx.x; int tid = threadIdx.x;
    __shared__ float sdec[AD], sw[AD], sgate[AD], sal[256], sE[256], red[256];
    __shared__ float sctx[2][AD];
    if (tid < AD) {
        float s = b_dec[tid];
        #pragma unroll
        for (int ks = 0; ks < NSA; ++ks) s += adg[((size_t)ks * BB + b) * 5120 + tid];
        sdec[tid] = s;
        sw[tid] = Wfull[tid];
    } else {
        int e = tid - AD;
        float s = b_fbeta[e];
        #pragma unroll
        for (int ks = 0; ks < NSA; ++ks) s += adg[((size_t)ks * BB + b) * 5120 + 512 + e];
        sgate[e] = s;
    }
    __syncthreads();
    int w = tid >> 6, lane = tid & 63;
    float4 sd0 = *(const float4*)&sdec[lane * 8];
    float4 sd1 = *(const float4*)&sdec[lane * 8 + 4];
    float4 sw0 = *(const float4*)&sw[lane * 8];
    float4 sw1 = *(const float4*)&sw[lane * 8 + 4];
    for (int p = w; p < PP; p += 16) {
        const _Float16* row = att_enc + ((size_t)b * PP + p) * AD + lane * 8;
        h16x8 hv = *(const h16x8*)row;
        float part = fmaxf((float)hv[0] + sd0.x, 0.f) * sw0.x +
                     fmaxf((float)hv[1] + sd0.y, 0.f) * sw0.y +
                     fmaxf((float)hv[2] + sd0.z, 0.f) * sw0.z +
                     fmaxf((float)hv[3] + sd0.w, 0.f) * sw0.w +
                     fmaxf((float)hv[4] + sd1.x, 0.f) * sw1.x +
                     fmaxf((float)hv[5] + sd1.y, 0.f) * sw1.y +
                     fmaxf((float)hv[6] + sd1.z, 0.f) * sw1.z +
                     fmaxf((float)hv[7] + sd1.w, 0.f) * sw1.w;
        #pragma unroll
        for (int off = 32; off > 0; off >>= 1) part += __shfl_down(part, off, 64);
        if (lane == 0) sE[p] = part;
    }
    __syncthreads();
    float myE = (tid < PP) ? sE[tid] : -1e30f;
    if (tid < 256) red[tid] = myE;
    __syncthreads();
    for (int s = 128; s > 0; s >>= 1) {
        if (tid < s) red[tid] = fmaxf(red[tid], red[tid + s]);
        __syncthreads();
    }
    float mx = red[0];
    __syncthreads();
    float ex = (tid < PP) ? __expf(myE - mx) : 0.f;
    if (tid < 256) red[tid] = ex;
    __syncthreads();
    for (int s = 128; s > 0; s >>= 1) {
        if (tid < s) red[tid] += red[tid + s];
        __syncthreads();
    }
    if (tid < PP) {
        float al = ex * (1.f / red[0]);
        sal[tid] = al;
        alpha_out[((size_t)b * TT + t) * PP + tid] = al;
    }
    __syncthreads();
    int e = tid & 511, half = tid >> 9;
    const unsigned short* basep = encb + (size_t)b * PP * ENCD + e;
    float s2 = 0.f;
    #pragma unroll 2
    for (int p = half * 98; p < half * 98 + 98; ++p)
        s2 += sal[p] * bf2f(basep[(size_t)p * ENCD]);
    sctx[half][e] = s2;
    __syncthreads();
    if (tid < AD) {
        float ctx = sctx[0][tid] + sctx[1][tid];
        float gate = sigf(sgate[tid]);
        unsigned short h, l; split2(gate * ctx, h, l);
        size_t o = ((size_t)(tid >> 3) * 64 + b) * 8 + (tid & 7);
        x2h[o] = h; x2l[o] = l;
    }
}

// ---- phase-3: gates = x2 @ Wih2(perm) + pregates + hWhh partials -> LSTM.
//      h written to axh (chunked, next step) AND hfc (chunked [kc][b*24+t][8], final GEMM). ----
__global__ __launch_bounds__(256) void gates_lstm2(
    const unsigned short* __restrict__ Ah, const unsigned short* __restrict__ Al,
    const unsigned short* __restrict__ Bh, const unsigned short* __restrict__ Bl,
    const float* __restrict__ pregates, const float* __restrict__ adg,
    float* __restrict__ c, unsigned short* __restrict__ ho_h,
    unsigned short* __restrict__ ho_l, unsigned short* __restrict__ hfc_h,
    unsigned short* __restrict__ hfc_l, int t) {
    __shared__ float gl[4][64][33];
    int tid = threadIdx.x, lane = tid & 63, w = tid >> 6;
    int n0 = blockIdx.x * 32;
    f32x4 acc[4][2];
    #pragma unroll
    for (int i = 0; i < 4; ++i)
        #pragma unroll
        for (int j = 0; j < 2; ++j) acc[i][j] = (f32x4){0.f, 0.f, 0.f, 0.f};
    #pragma unroll
    for (int s = 0; s < 4; ++s) {
        int kc = w * 16 + s * 4 + (lane >> 4);
        short8 afh[4], afl[4], bfh[2], bfl[2];
        #pragma unroll
        for (int mi = 0; mi < 4; ++mi) {
            size_t o = ((size_t)kc * 64 + mi * 16 + (lane & 15)) * 8;
            afh[mi] = *(const short8*)(Ah + o);
            afl[mi] = *(const short8*)(Al + o);
        }
        #pragma unroll
        for (int ni = 0; ni < 2; ++ni) {
            size_t o = ((size_t)kc * 4096 + n0 + ni * 16 + (lane & 15)) * 8;
            bfh[ni] = *(const short8*)(Bh + o);
            bfl[ni] = *(const short8*)(Bl + o);
        }
        #pragma unroll
        for (int mi = 0; mi < 4; ++mi)
            #pragma unroll
            for (int ni = 0; ni < 2; ++ni) {
                acc[mi][ni] = __builtin_amdgcn_mfma_f32_16x16x32_bf16(afh[mi], bfh[ni], acc[mi][ni], 0, 0, 0);
                acc[mi][ni] = __builtin_amdgcn_mfma_f32_16x16x32_bf16(afh[mi], bfl[ni], acc[mi][ni], 0, 0, 0);
                acc[mi][ni] = __builtin_amdgcn_mfma_f32_16x16x32_bf16(afl[mi], bfh[ni], acc[mi][ni], 0, 0, 0);
            }
    }
    #pragma unroll
    for (int mi = 0; mi < 4; ++mi) {
        int rrow = mi * 16 + ((lane >> 4) << 2);
        #pragma unroll
        for (int ni = 0; ni < 2; ++ni) {
            int cl = ni * 16 + (lane & 15);
            #pragma unroll
            for (int qq = 0; qq < 4; ++qq)
                gl[w][rrow + qq][cl] = acc[mi][ni][qq];
        }
    }
    __syncthreads();
    #pragma unroll
    for (int i = 0; i < 2; ++i) {
        int idx = tid + i * 256;
        int b = idx >> 3, jl = idx & 7;
        float g4[4];
        #pragma unroll
        for (int qq = 0; qq < 4; ++qq)
            g4[qq] = gl[0][b][4 * jl + qq] + gl[1][b][4 * jl + qq] +
                     gl[2][b][4 * jl + qq] + gl[3][b][4 * jl + qq];
        {
            float4 pv = *(const float4*)&pregates[((size_t)(t * 64 + b)) * 4096 + n0 + 4 * jl];
            g4[0] += pv.x; g4[1] += pv.y; g4[2] += pv.z; g4[3] += pv.w;
        }
        #pragma unroll
        for (int ks = 0; ks < NSA; ++ks) {
            float4 av = *(const float4*)&adg[((size_t)ks * BB + b) * 5120 + 1024 + n0 + 4 * jl];
            g4[0] += av.x; g4[1] += av.y; g4[2] += av.z; g4[3] += av.w;
        }
        int j = (n0 >> 2) + jl;
        float cn = sigf(g4[1]) * c[b * HD + j] + sigf(g4[0]) * tanhf(g4[2]);
        c[b * HD + j] = cn;
        float hn = sigf(g4[3]) * tanhf(cn);
        unsigned short h, l; split2(hn, h, l);
        size_t o1 = ((size_t)(j >> 3) * 64 + b) * 8 + (j & 7);
        ho_h[o1] = h; ho_l[o1] = l;
        size_t o2 = ((size_t)(j >> 3) * (TT * BB) + b * TT + t) * 8 + (j & 7);
        hfc_h[o2] = h; hfc_l[o2] = l;
    }
}

extern "C" void kernel_launch(void* const* d_in, const int* in_sizes, int n_in,
                              void* d_out, int out_size, void* d_ws, size_t ws_size,
                              hipStream_t stream) {
    const float* enc      = (const float*)d_in[0];
    const int*   captions = (const int*)d_in[1];
    const float* W_enc    = (const float*)d_in[3];
    const float* b_enc    = (const float*)d_in[4];
    const float* W_dec    = (const float*)d_in[5];
    const float* b_dec    = (const float*)d_in[6];
    const float* W_full   = (const float*)d_in[7];
    const float* table    = (const float*)d_in[9];
    const float* W_ih     = (const float*)d_in[10];   // [1536][4096]
    const float* b_ih     = (const float*)d_in[11];
    const float* W_hh     = (const float*)d_in[12];   // [1024][4096]
    const float* b_hh     = (const float*)d_in[13];
    const float* W_init_h = (const float*)d_in[14];
    const float* b_init_h = (const float*)d_in[15];
    const float* W_init_c = (const float*)d_in[16];
    const float* b_init_c = (const float*)d_in[17];
    const float* W_fbeta  = (const float*)d_in[18];
    const float* b_fbeta  = (const float*)d_in[19];
    const float* W_fc     = (const float*)d_in[20];
    const float* b_fc     = (const float*)d_in[21];

    float* preds  = (float*)d_out;                         // [64][24][20000]
    float* alphas = (float*)d_out + (size_t)BB * TT * VD;  // [64][24][196]

    // ---- workspace carve. Front region dead after loop -> wfc overlays.
    //      encb aliases wih1 (dead after pregates GEMM). embc/adg share scratch0. ----
    char* base = (char*)d_ws;
    size_t off = 0;
    auto take = [&](size_t b) { void* r = (void*)(base + off); off += (b + 255) & ~(size_t)255; return r; };
    _Float16* att_enc = (_Float16*)take((size_t)12544 * 512 * 2);                // 12.9 MB (fp16)
    unsigned short* wbig_h = (unsigned short*)take((size_t)128 * 5120 * 8 * 2);  // 10.5 x2
    unsigned short* wbig_l = (unsigned short*)take((size_t)128 * 5120 * 8 * 2);
    unsigned short* wih1_h = (unsigned short*)take((size_t)128 * 4096 * 8 * 2);  // 8.4 x2
    unsigned short* wih1_l = (unsigned short*)take((size_t)128 * 4096 * 8 * 2);
    unsigned short* encb   = (unsigned short*)wih1_h;   // 12.85 MB <= 16.8 MB, written after pregates GEMM
    unsigned short* wih2_h = (unsigned short*)take((size_t)64 * 4096 * 8 * 2);   // 4.2 x2
    unsigned short* wih2_l = (unsigned short*)take((size_t)64 * 4096 * 8 * 2);
    unsigned short* wenc_h = (unsigned short*)take((size_t)64 * 512 * 8 * 2);    // 0.52 x2
    unsigned short* wenc_l = (unsigned short*)take((size_t)64 * 512 * 8 * 2);
    float* pregates = (float*)take((size_t)TT * BB * 4096 * 4);                  // 25.2
    float* scratch0 = (float*)take((size_t)TT * BB * ED * 4);                    // 6.3 (embc / adg union)
    unsigned short* embc_h = (unsigned short*)scratch0;                          // 3.15
    unsigned short* embc_l = embc_h + (size_t)128 * TT * BB * 8;                 // 3.15
    float* adg      = scratch0;   // NSA*64*5120*4 = 5.24 MB <= 6.3 MB (embc dead after pregates GEMM)
    float* biasp    = (float*)take((size_t)4096 * 4);
    // wfc overlays [0, off): written AFTER the loop
    unsigned short* wfc_h = (unsigned short*)(base);
    unsigned short* wfc_l = (unsigned short*)(base + (size_t)128 * VPAD * 8 * 2);
    // persistent (live across wfc write):
    float* c_buf = (float*)take((size_t)BB * HD * 4);
    float* mf    = (float*)take((size_t)BB * ENCD * 4);
    unsigned short* axh_h0 = (unsigned short*)take((size_t)192 * 64 * 8 * 2);
    unsigned short* axh_l0 = (unsigned short*)take((size_t)192 * 64 * 8 * 2);
    unsigned short* axh_h1 = (unsigned short*)take((size_t)192 * 64 * 8 * 2);
    unsigned short* axh_l1 = (unsigned short*)take((size_t)192 * 64 * 8 * 2);
    unsigned short* hfc_h  = (unsigned short*)take((size_t)128 * TT * BB * 8 * 2); // 3.15 x2
    unsigned short* hfc_l  = (unsigned short*)take((size_t)128 * TT * BB * 8 * 2);

    // ---- prologue ----
    megasplit_kernel<<<7312, 256, 0, stream>>>(
        W_enc, wenc_h, wenc_l, W_dec, W_fbeta, W_hh, wbig_h, wbig_l,
        W_ih, wih1_h, wih1_l, wih2_h, wih2_l,
        b_ih, b_hh, biasp, captions, table, embc_h, embc_l);
    mean_kernel<<<BB, 512, 0, stream>>>(enc, mf);
    init_hc_kernel<<<dim3(BB, 2), 256, 0, stream>>>(mf, W_init_h, b_init_h, W_init_c, b_init_c,
                                                    axh_h0 + HOFF, axh_l0 + HOFF, c_buf);
    // att_enc(fp16) = enc @ W_enc + b_enc : M=12544 N=512 K=512 (A fp32 in-kernel split)
    mfma_gemm_bigf<<<392, 256, 0, stream>>>(enc, wenc_h, wenc_l, b_enc, (float*)att_enc,
                                            512, 512, 512, 98, 4, 0, 1);
    // pregates = emb(chunked) @ W_ih[0:1024](perm) + biasp : M=1536 N=4096 K=1024
    mfma_gemm_bigp<<<384, 256, 0, stream>>>(embc_h, embc_l, wih1_h, wih1_l, biasp, pregates,
                                            TT * BB, 4096, 4096, 1024, 12, 32, 1);
    // enc -> bf16 (context operand); aliases wih1 which is now dead
    enc2bf16_kernel<<<3136, 256, 0, stream>>>(enc, encb);

    // ---- step loop: 3 dispatches/step ----
    {
        unsigned short* ah[2] = {axh_h0, axh_h1};
        unsigned short* al[2] = {axh_l0, axh_l1};
        for (int t = 0; t < TT; ++t) {
            int par = t & 1;
            hgemm_direct<<<dim3(40, NSA), 256, 0, stream>>>(
                ah[par] + HOFF, al[par] + HOFF, wbig_h, wbig_l, adg);
            attn_ctx_kernel<<<BB, 1024, 0, stream>>>(att_enc, adg, b_dec, W_full, encb,
                                                     b_fbeta, alphas, ah[par], al[par], t);
            gates_lstm2<<<128, 256, 0, stream>>>(
                ah[par], al[par], wih2_h, wih2_l, pregates, adg, c_buf,
                ah[1 - par] + HOFF, al[1 - par] + HOFF, hfc_h, hfc_l, t);
        }
    }

    // ---- epilogue: wfc split into aliased region; final GEMM with pre-split A ----
    split_w_kernel<<<dim3(79, 128), 256, 0, stream>>>(W_fc, wfc_h, wfc_l, VD, VPAD, 0, VPAD, 0, 0);
    mfma_gemm_bigp<<<1884, 256, 0, stream>>>(hfc_h, hfc_l, wfc_h, wfc_l, b_fc, preds,
                                             TT * BB, VD, VPAD, 1024, 12, 157, 1);
}

// Round 14
// 1468.988 us; speedup vs baseline: 1.0424x; 1.0295x over previous
//
#include <hip/hip_runtime.h>
#include <hip/hip_bf16.h>

// Problem dims (fixed)
#define BB 64
#define PP 196
#define ENCD 512
#define ED 1024
#define HD 1024
#define AD 512
#define VD 20000
#define TT 24
#define VPAD 20096
#define HOFF 32768 // h-part offset (shorts) inside axh
#define NSA 4      // adg K-splits

typedef __attribute__((ext_vector_type(8))) short short8;
typedef __attribute__((ext_vector_type(4))) short short4v;
typedef __attribute__((ext_vector_type(4))) float f32x4;
typedef __attribute__((ext_vector_type(8))) _Float16 h16x8;

__device__ __forceinline__ float sigf(float x) { return 1.f / (1.f + __expf(-x)); }

__device__ __forceinline__ unsigned short f2bf(float f) {
    unsigned u = __builtin_bit_cast(unsigned, f);
    u = (u + 0x7FFFu + ((u >> 16) & 1u)) >> 16;
    return (unsigned short)u;
}
__device__ __forceinline__ void split2(float v, unsigned short& h, unsigned short& l) {
    h = f2bf(v);
    float hf = __builtin_bit_cast(float, ((unsigned)h) << 16);
    l = f2bf(v - hf);
}
__device__ __forceinline__ void split2h(float v, _Float16& h, _Float16& l) {
    h = (_Float16)v;
    l = (_Float16)(v - (float)h);
}
__device__ __forceinline__ float bf2f(unsigned short u) {
    return __builtin_bit_cast(float, ((unsigned)u) << 16);
}

// ---- split-store helper: one (kc, n-group) of a weight split job ----
__device__ __forceinline__ void split_store(
    const float* __restrict__ W, unsigned short* __restrict__ oh,
    unsigned short* __restrict__ ol, int N, int Npad, int coff,
    int rowoff, int perm, int kc, int n) {
    int src = perm ? ((n & 3) * 1024 + (n >> 2)) : n;
    short8 vh, vl;
    #pragma unroll
    for (int j = 0; j < 8; ++j) {
        float v = (src < N) ? W[(size_t)(rowoff + kc * 8 + j) * N + src] : 0.f;
        unsigned short h, l; split2(v, h, l);
        vh[j] = (short)h; vl[j] = (short)l;
    }
    size_t o = ((size_t)kc * Npad + coff + n) * 8;
    *(short8*)(oh + o) = vh; *(short8*)(ol + o) = vl;
}

// ---- mega prologue kernel: weight splits + bias_perm + embed gather-split ----
__global__ __launch_bounds__(256) void megasplit_kernel(
    const float* __restrict__ W_enc, unsigned short* __restrict__ wenc_h, unsigned short* __restrict__ wenc_l,
    const float* __restrict__ W_dec, const float* __restrict__ W_fbeta, const float* __restrict__ W_hh,
    unsigned short* __restrict__ wbig_h, unsigned short* __restrict__ wbig_l,
    const float* __restrict__ W_ih,
    unsigned short* __restrict__ wih1_h, unsigned short* __restrict__ wih1_l,
    unsigned short* __restrict__ wih2_h, unsigned short* __restrict__ wih2_l,
    const float* __restrict__ b_ih, const float* __restrict__ b_hh, float* __restrict__ biasp,
    const int* __restrict__ captions, const float* __restrict__ table,
    unsigned short* __restrict__ embc_h, unsigned short* __restrict__ embc_l) {
    int bid = blockIdx.x, tid = threadIdx.x;
    if (bid < 128) {
        int local = bid, xb = local & 1, kc = local >> 1;
        split_store(W_enc, wenc_h, wenc_l, 512, 512, 0, 0, 0, kc, xb * 256 + tid);
    } else if (bid < 384) {
        int local = bid - 128, xb = local & 1, kc = local >> 1;
        split_store(W_dec, wbig_h, wbig_l, 512, 5120, 0, 0, 0, kc, xb * 256 + tid);
    } else if (bid < 640) {
        int local = bid - 384, xb = local & 1, kc = local >> 1;
        split_store(W_fbeta, wbig_h, wbig_l, 512, 5120, 512, 0, 0, kc, xb * 256 + tid);
    } else if (bid < 2688) {
        int local = bid - 640, xb = local & 15, kc = local >> 4;
        split_store(W_hh, wbig_h, wbig_l, 4096, 5120, 1024, 0, 1, kc, xb * 256 + tid);
    } else if (bid < 4736) {
        int local = bid - 2688, xb = local & 15, kc = local >> 4;
        split_store(W_ih, wih1_h, wih1_l, 4096, 4096, 0, 0, 1, kc, xb * 256 + tid);
    } else if (bid < 5760) {
        int local = bid - 4736, xb = local & 15, kc = local >> 4;
        split_store(W_ih, wih2_h, wih2_l, 4096, 4096, 0, 1024, 1, kc, xb * 256 + tid);
    } else if (bid < 5776) {
        int n = (bid - 5760) * 256 + tid;
        int src = (n & 3) * 1024 + (n >> 2);
        biasp[n] = b_ih[src] + b_hh[src];
    } else {
        // embed gather + split -> chunked [kc][t*64+b][8] hi/lo
        int local = bid - 5776;
        int t = local >> 6, b = local & 63;
        if (tid < 128) {
            int kc = tid;
            int tok = captions[b * 25 + t];
            const float* row = table + (size_t)tok * ED + kc * 8;
            short8 vh, vl;
            #pragma unroll
            for (int j = 0; j < 8; ++j) {
                unsigned short h, l; split2(row[j], h, l);
                vh[j] = (short)h; vl[j] = (short)l;
            }
            size_t o = ((size_t)kc * (TT * BB) + t * BB + b) * 8;
            *(short8*)(embc_h + o) = vh; *(short8*)(embc_l + o) = vl;
        }
    }
}

// ---- enc -> bf16 copy (context-phase operand) ----
__global__ __launch_bounds__(256) void enc2bf16_kernel(
    const float* __restrict__ enc, unsigned short* __restrict__ encb) {
    size_t idx = ((size_t)blockIdx.x * 256 + threadIdx.x) * 8;
    float4 v0 = *(const float4*)(enc + idx);
    float4 v1 = *(const float4*)(enc + idx + 4);
    short8 o;
    o[0] = (short)f2bf(v0.x); o[1] = (short)f2bf(v0.y);
    o[2] = (short)f2bf(v0.z); o[3] = (short)f2bf(v0.w);
    o[4] = (short)f2bf(v1.x); o[5] = (short)f2bf(v1.y);
    o[6] = (short)f2bf(v1.z); o[7] = (short)f2bf(v1.w);
    *(short8*)(encb + idx) = o;
}

// ---- wfc split: fp32 [K][N] -> single fp16 chunked [kc][Npad][8] ----
__global__ __launch_bounds__(256) void split_w_fp16_kernel(
    const float* __restrict__ W, _Float16* __restrict__ oq,
    int N, int Npad, int Nlaunch) {
    int n = blockIdx.x * 256 + threadIdx.x;
    if (n >= Nlaunch) return;
    int kc = blockIdx.y;
    h16x8 v;
    #pragma unroll
    for (int j = 0; j < 8; ++j)
        v[j] = (_Float16)((n < N) ? W[(size_t)(kc * 8 + j) * N + n] : 0.f);
    *(h16x8*)(oq + ((size_t)kc * Npad + n) * 8) = v;
}

__global__ __launch_bounds__(512) void mean_kernel(const float* __restrict__ enc,
                                                   float* __restrict__ mf) {
    int b = blockIdx.x; int e = threadIdx.x;
    const float* base = enc + (size_t)b * PP * ENCD + e;
    float s = 0.f;
    #pragma unroll 4
    for (int p = 0; p < PP; ++p) s += base[(size_t)p * ENCD];
    mf[b * ENCD + e] = s * (1.f / PP);
}

__global__ __launch_bounds__(256) void init_hc_kernel(
    const float* __restrict__ mf,
    const float* __restrict__ Wh, const float* __restrict__ bh,
    const float* __restrict__ Wc, const float* __restrict__ bc,
    unsigned short* __restrict__ hc_h, unsigned short* __restrict__ hc_l,
    float* __restrict__ c0) {
    int b = blockIdx.x;
    int isC = blockIdx.y;
    const float* W    = isC ? Wc : Wh;
    const float* bias = isC ? bc : bh;
    __shared__ float smf[ENCD];
    for (int i = threadIdx.x; i < ENCD; i += 256) smf[i] = mf[b * ENCD + i];
    __syncthreads();
    #pragma unroll
    for (int jj = 0; jj < 4; ++jj) {
        int j = threadIdx.x + jj * 256;
        float acc = bias[j];
        for (int k = 0; k < ENCD; ++k) acc += smf[k] * W[(size_t)k * HD + j];
        if (isC) c0[b * HD + j] = acc;
        else {
            unsigned short h, l; split2(acc, h, l);
            size_t o = ((size_t)(j >> 3) * 64 + b) * 8 + (j & 7);
            hc_h[o] = h; hc_l[o] = l;
        }
    }
}

// ---- big MFMA GEMM, A fp32 (in-kernel split) — used for att_enc only ----
__global__ __launch_bounds__(256) void mfma_gemm_bigf(
    const float* __restrict__ Ap,
    const unsigned short* __restrict__ Bh, const unsigned short* __restrict__ Bl,
    const float* __restrict__ bias, float* __restrict__ C,
    int N, int Npad, int K, int Mtiles, int Ntiles, int inner_m, int half_out) {
    __shared__ __align__(16) short lds[32768];
    short* Ahs = lds;
    short* Als = lds + 8192;
    short* Bhs = lds + 16384;
    short* Bls = lds + 24576;
    int tid = threadIdx.x, lane = tid & 63, w = tid >> 6;
    int nwg = Mtiles * Ntiles;
    int orig = blockIdx.x;
    int q = nwg >> 3, r = nwg & 7;
    int xcd = orig & 7;
    int basew = (xcd < r) ? xcd * (q + 1) : r * (q + 1) + (xcd - r) * q;
    int wg = basew + (orig >> 3);
    int mt, nt;
    if (inner_m) { mt = wg % Mtiles; nt = wg / Mtiles; }
    else         { nt = wg % Ntiles; mt = wg / Ntiles; }
    int m0 = mt * 128, n0 = nt * 128;
    int wr = w >> 1, wc = w & 1;
    f32x4 acc[4][4];
    #pragma unroll
    for (int i = 0; i < 4; ++i)
        #pragma unroll
        for (int j = 0; j < 4; ++j) acc[i][j] = (f32x4){0.f, 0.f, 0.f, 0.f};
    int nsteps = K >> 6;
    float4 va[8];
    short8 rb[2][4];
    auto load_step = [&](int s) {
        int k0 = s * 64, kc0 = s * 8;
        #pragma unroll
        for (int it = 0; it < 8; ++it) {
            int idx = it * 256 + tid; int m = idx >> 4, k4 = idx & 15;
            va[it] = *(const float4*)(Ap + (size_t)(m0 + m) * K + k0 + k4 * 4);
        }
        #pragma unroll
        for (int it = 0; it < 4; ++it) {
            int g = w * 4 + it; int kcl = g >> 1; int rb0 = (g & 1) * 64;
            size_t gb = ((size_t)(kc0 + kcl) * Npad + n0 + rb0 + lane) * 8;
            rb[0][it] = *(const short8*)(Bh + gb);
            rb[1][it] = *(const short8*)(Bl + gb);
        }
    };
    load_step(0);
    for (int s = 0; s < nsteps; ++s) {
        __syncthreads();
        #pragma unroll
        for (int it = 0; it < 8; ++it) {
            int idx = it * 256 + tid; int m = idx >> 4, k4 = idx & 15;
            int kc = k4 >> 1, jh = (k4 & 1) * 4;
            float vv[4] = {va[it].x, va[it].y, va[it].z, va[it].w};
            short4v hv, lv;
            #pragma unroll
            for (int qq = 0; qq < 4; ++qq) {
                unsigned short h, l; split2(vv[qq], h, l);
                hv[qq] = (short)h; lv[qq] = (short)l;
            }
            int o = kc * 1024 + ((m ^ kc) << 3) + jh;
            *(short4v*)(Ahs + o) = hv;
            *(short4v*)(Als + o) = lv;
        }
        #pragma unroll
        for (int it = 0; it < 4; ++it) {
            int g = w * 4 + it; int kcl = g >> 1; int rb0 = (g & 1) * 64;
            int o = (kcl * 128 + rb0 + lane) * 8;
            *(short8*)(Bhs + o) = rb[0][it];
            *(short8*)(Bls + o) = rb[1][it];
        }
        __syncthreads();
        if (s + 1 < nsteps) load_step(s + 1);
        #pragma unroll
        for (int ks = 0; ks < 2; ++ks) {
            int kq = ks * 4 + (lane >> 4);
            short8 afh[4], afl[4], bfh[4], bfl[4];
            #pragma unroll
            for (int mi = 0; mi < 4; ++mi) {
                int row = wr * 64 + mi * 16 + (lane & 15);
                int o = kq * 1024 + ((row ^ kq) << 3);
                afh[mi] = *(const short8*)(Ahs + o);
                afl[mi] = *(const short8*)(Als + o);
            }
            #pragma unroll
            for (int ni = 0; ni < 4; ++ni) {
                int o = (kq * 128 + wc * 64 + ni * 16 + (lane & 15)) * 8;
                bfh[ni] = *(const short8*)(Bhs + o);
                bfl[ni] = *(const short8*)(Bls + o);
            }
            #pragma unroll
            for (int mi = 0; mi < 4; ++mi)
                #pragma unroll
                for (int ni = 0; ni < 4; ++ni) {
                    acc[mi][ni] = __builtin_amdgcn_mfma_f32_16x16x32_bf16(afh[mi], bfh[ni], acc[mi][ni], 0, 0, 0);
                    acc[mi][ni] = __builtin_amdgcn_mfma_f32_16x16x32_bf16(afh[mi], bfl[ni], acc[mi][ni], 0, 0, 0);
                    acc[mi][ni] = __builtin_amdgcn_mfma_f32_16x16x32_bf16(afl[mi], bfh[ni], acc[mi][ni], 0, 0, 0);
                }
        }
    }
    #pragma unroll
    for (int mi = 0; mi < 4; ++mi) {
        int rrow = m0 + wr * 64 + mi * 16 + ((lane >> 4) << 2);
        #pragma unroll
        for (int ni = 0; ni < 4; ++ni) {
            int c = n0 + wc * 64 + ni * 16 + (lane & 15);
            if (c < N) {
                float bv = bias ? bias[c] : 0.f;
                if (half_out) {
                    _Float16* Ch = (_Float16*)C;
                    #pragma unroll
                    for (int qq = 0; qq < 4; ++qq)
                        Ch[(size_t)(rrow + qq) * N + c] = (_Float16)(acc[mi][ni][qq] + bv);
                } else {
                    #pragma unroll
                    for (int qq = 0; qq < 4; ++qq)
                        C[(size_t)(rrow + qq) * N + c] = acc[mi][ni][qq] + bv;
                }
            }
        }
    }
}

// ---- big MFMA GEMM, A pre-split chunked bf16 hi/lo — pregates ----
__global__ __launch_bounds__(256) void mfma_gemm_bigp(
    const unsigned short* __restrict__ Ah, const unsigned short* __restrict__ Al,
    const unsigned short* __restrict__ Bh, const unsigned short* __restrict__ Bl,
    const float* __restrict__ bias, float* __restrict__ C,
    int Mtot, int N, int Npad, int K, int Mtiles, int Ntiles, int inner_m) {
    __shared__ __align__(16) short lds[32768];
    short* Ahs = lds;
    short* Als = lds + 8192;
    short* Bhs = lds + 16384;
    short* Bls = lds + 24576;
    int tid = threadIdx.x, lane = tid & 63, w = tid >> 6;
    int nwg = Mtiles * Ntiles;
    int orig = blockIdx.x;
    int q = nwg >> 3, r = nwg & 7;
    int xcd = orig & 7;
    int basew = (xcd < r) ? xcd * (q + 1) : r * (q + 1) + (xcd - r) * q;
    int wg = basew + (orig >> 3);
    int mt, nt;
    if (inner_m) { mt = wg % Mtiles; nt = wg / Mtiles; }
    else         { nt = wg % Ntiles; mt = wg / Ntiles; }
    int m0 = mt * 128, n0 = nt * 128;
    int wr = w >> 1, wc = w & 1;
    f32x4 acc[4][4];
    #pragma unroll
    for (int i = 0; i < 4; ++i)
        #pragma unroll
        for (int j = 0; j < 4; ++j) acc[i][j] = (f32x4){0.f, 0.f, 0.f, 0.f};
    int nsteps = K >> 6;
    short8 ra[2][4], rb[2][4];
    auto load_step = [&](int s) {
        int kc0 = s * 8;
        #pragma unroll
        for (int it = 0; it < 4; ++it) {
            int idx = it * 256 + tid; int kcl = idx >> 7, row = idx & 127;
            size_t ga = ((size_t)(kc0 + kcl) * Mtot + m0 + row) * 8;
            ra[0][it] = *(const short8*)(Ah + ga);
            ra[1][it] = *(const short8*)(Al + ga);
        }
        #pragma unroll
        for (int it = 0; it < 4; ++it) {
            int g = w * 4 + it; int kcl = g >> 1; int rb0 = (g & 1) * 64;
            size_t gb = ((size_t)(kc0 + kcl) * Npad + n0 + rb0 + lane) * 8;
            rb[0][it] = *(const short8*)(Bh + gb);
            rb[1][it] = *(const short8*)(Bl + gb);
        }
    };
    load_step(0);
    for (int s = 0; s < nsteps; ++s) {
        __syncthreads();
        #pragma unroll
        for (int it = 0; it < 4; ++it) {
            int idx = it * 256 + tid; int kcl = idx >> 7, row = idx & 127;
            int o = (kcl * 128 + row) * 8;
            *(short8*)(Ahs + o) = ra[0][it];
            *(short8*)(Als + o) = ra[1][it];
        }
        #pragma unroll
        for (int it = 0; it < 4; ++it) {
            int g = w * 4 + it; int kcl = g >> 1; int rb0 = (g & 1) * 64;
            int o = (kcl * 128 + rb0 + lane) * 8;
            *(short8*)(Bhs + o) = rb[0][it];
            *(short8*)(Bls + o) = rb[1][it];
        }
        __syncthreads();
        if (s + 1 < nsteps) load_step(s + 1);
        #pragma unroll
        for (int ks = 0; ks < 2; ++ks) {
            int kq = ks * 4 + (lane >> 4);
            short8 afh[4], afl[4], bfh[4], bfl[4];
            #pragma unroll
            for (int mi = 0; mi < 4; ++mi) {
                int o = (kq * 128 + wr * 64 + mi * 16 + (lane & 15)) * 8;
                afh[mi] = *(const short8*)(Ahs + o);
                afl[mi] = *(const short8*)(Als + o);
            }
            #pragma unroll
            for (int ni = 0; ni < 4; ++ni) {
                int o = (kq * 128 + wc * 64 + ni * 16 + (lane & 15)) * 8;
                bfh[ni] = *(const short8*)(Bhs + o);
                bfl[ni] = *(const short8*)(Bls + o);
            }
            #pragma unroll
            for (int mi = 0; mi < 4; ++mi)
                #pragma unroll
                for (int ni = 0; ni < 4; ++ni) {
                    acc[mi][ni] = __builtin_amdgcn_mfma_f32_16x16x32_bf16(afh[mi], bfh[ni], acc[mi][ni], 0, 0, 0);
                    acc[mi][ni] = __builtin_amdgcn_mfma_f32_16x16x32_bf16(afh[mi], bfl[ni], acc[mi][ni], 0, 0, 0);
                    acc[mi][ni] = __builtin_amdgcn_mfma_f32_16x16x32_bf16(afl[mi], bfh[ni], acc[mi][ni], 0, 0, 0);
                }
        }
    }
    #pragma unroll
    for (int mi = 0; mi < 4; ++mi) {
        int rrow = m0 + wr * 64 + mi * 16 + ((lane >> 4) << 2);
        #pragma unroll
        for (int ni = 0; ni < 4; ++ni) {
            int c = n0 + wc * 64 + ni * 16 + (lane & 15);
            if (c < N) {
                float bv = bias ? bias[c] : 0.f;
                #pragma unroll
                for (int qq = 0; qq < 4; ++qq)
                    C[(size_t)(rrow + qq) * N + c] = acc[mi][ni][qq] + bv;
            }
        }
    }
}

// ---- final GEMM: A pre-split fp16 hi/lo chunked, B single fp16 chunked. 2-pass. ----
__global__ __launch_bounds__(256) void mfma_gemm_fp16(
    const _Float16* __restrict__ Ah, const _Float16* __restrict__ Al,
    const _Float16* __restrict__ Bq,
    const float* __restrict__ bias, float* __restrict__ C,
    int Mtot, int N, int Npad, int K, int Mtiles, int Ntiles) {
    __shared__ __align__(16) _Float16 lds[24576];   // 48 KB
    _Float16* Ahs = lds;            // [8][128][8]
    _Float16* Als = lds + 8192;
    _Float16* Bs  = lds + 16384;    // [8][128][8]
    int tid = threadIdx.x, lane = tid & 63, w = tid >> 6;
    int nwg = Mtiles * Ntiles;
    int orig = blockIdx.x;
    int q = nwg >> 3, r = nwg & 7;
    int xcd = orig & 7;
    int basew = (xcd < r) ? xcd * (q + 1) : r * (q + 1) + (xcd - r) * q;
    int wg = basew + (orig >> 3);
    int mt = wg % Mtiles, nt = wg / Mtiles;   // inner_m (share B panels)
    int m0 = mt * 128, n0 = nt * 128;
    int wr = w >> 1, wc = w & 1;
    f32x4 acc[4][4];
    #pragma unroll
    for (int i = 0; i < 4; ++i)
        #pragma unroll
        for (int j = 0; j < 4; ++j) acc[i][j] = (f32x4){0.f, 0.f, 0.f, 0.f};
    int nsteps = K >> 6;
    h16x8 ra[2][4], rb[4];
    auto load_step = [&](int s) {
        int kc0 = s * 8;
        #pragma unroll
        for (int it = 0; it < 4; ++it) {
            int idx = it * 256 + tid; int kcl = idx >> 7, row = idx & 127;
            size_t ga = ((size_t)(kc0 + kcl) * Mtot + m0 + row) * 8;
            ra[0][it] = *(const h16x8*)(Ah + ga);
            ra[1][it] = *(const h16x8*)(Al + ga);
        }
        #pragma unroll
        for (int it = 0; it < 4; ++it) {
            int idx = it * 256 + tid; int kcl = idx >> 7, row = idx & 127;
            size_t gb = ((size_t)(kc0 + kcl) * Npad + n0 + row) * 8;
            rb[it] = *(const h16x8*)(Bq + gb);
        }
    };
    load_step(0);
    for (int s = 0; s < nsteps; ++s) {
        __syncthreads();
        #pragma unroll
        for (int it = 0; it < 4; ++it) {
            int idx = it * 256 + tid; int kcl = idx >> 7, row = idx & 127;
            int o = (kcl * 128 + row) * 8;
            *(h16x8*)(Ahs + o) = ra[0][it];
            *(h16x8*)(Als + o) = ra[1][it];
            *(h16x8*)(Bs + o)  = rb[it];
        }
        __syncthreads();
        if (s + 1 < nsteps) load_step(s + 1);
        #pragma unroll
        for (int ks = 0; ks < 2; ++ks) {
            int kq = ks * 4 + (lane >> 4);
            h16x8 afh[4], afl[4], bf[4];
            #pragma unroll
            for (int mi = 0; mi < 4; ++mi) {
                int o = (kq * 128 + wr * 64 + mi * 16 + (lane & 15)) * 8;
                afh[mi] = *(const h16x8*)(Ahs + o);
                afl[mi] = *(const h16x8*)(Als + o);
            }
            #pragma unroll
            for (int ni = 0; ni < 4; ++ni) {
                int o = (kq * 128 + wc * 64 + ni * 16 + (lane & 15)) * 8;
                bf[ni] = *(const h16x8*)(Bs + o);
            }
            #pragma unroll
            for (int mi = 0; mi < 4; ++mi)
                #pragma unroll
                for (int ni = 0; ni < 4; ++ni) {
                    acc[mi][ni] = __builtin_amdgcn_mfma_f32_16x16x32_f16(afh[mi], bf[ni], acc[mi][ni], 0, 0, 0);
                    acc[mi][ni] = __builtin_amdgcn_mfma_f32_16x16x32_f16(afl[mi], bf[ni], acc[mi][ni], 0, 0, 0);
                }
        }
    }
    #pragma unroll
    for (int mi = 0; mi < 4; ++mi) {
        int rrow = m0 + wr * 64 + mi * 16 + ((lane >> 4) << 2);
        #pragma unroll
        for (int ni = 0; ni < 4; ++ni) {
            int c = n0 + wc * 64 + ni * 16 + (lane & 15);
            if (c < N) {
                float bv = bias ? bias[c] : 0.f;
                #pragma unroll
                for (int qq = 0; qq < 4; ++qq)
                    C[(size_t)(rrow + qq) * N + c] = acc[mi][ni][qq] + bv;
            }
        }
    }
}

// ---- phase-1: adg = h @ [W_dec|W_fbeta|Whh(perm)] — zero-barrier, Ksplit=4 ----
__global__ __launch_bounds__(256) void hgemm_direct(
    const unsigned short* __restrict__ Ah, const unsigned short* __restrict__ Al,
    const unsigned short* __restrict__ Bh, const unsigned short* __restrict__ Bl,
    float* __restrict__ out) {
    int tid = threadIdx.x, lane = tid & 63, w = tid >> 6;
    int n0 = blockIdx.x * 128 + w * 32;
    int kc0 = blockIdx.y * 32;
    out += (size_t)blockIdx.y * 64 * 5120;
    f32x4 acc[4][2];
    #pragma unroll
    for (int i = 0; i < 4; ++i)
        #pragma unroll
        for (int j = 0; j < 2; ++j) acc[i][j] = (f32x4){0.f, 0.f, 0.f, 0.f};
    #pragma unroll
    for (int s = 0; s < 8; ++s) {
        int kc = kc0 + s * 4 + (lane >> 4);
        short8 afh[4], afl[4], bfh[2], bfl[2];
        #pragma unroll
        for (int mi = 0; mi < 4; ++mi) {
            size_t o = ((size_t)kc * 64 + mi * 16 + (lane & 15)) * 8;
            afh[mi] = *(const short8*)(Ah + o);
            afl[mi] = *(const short8*)(Al + o);
        }
        #pragma unroll
        for (int ni = 0; ni < 2; ++ni) {
            size_t o = ((size_t)kc * 5120 + n0 + ni * 16 + (lane & 15)) * 8;
            bfh[ni] = *(const short8*)(Bh + o);
            bfl[ni] = *(const short8*)(Bl + o);
        }
        #pragma unroll
        for (int mi = 0; mi < 4; ++mi)
            #pragma unroll
            for (int ni = 0; ni < 2; ++ni) {
                acc[mi][ni] = __builtin_amdgcn_mfma_f32_16x16x32_bf16(afh[mi], bfh[ni], acc[mi][ni], 0, 0, 0);
                acc[mi][ni] = __builtin_amdgcn_mfma_f32_16x16x32_bf16(afh[mi], bfl[ni], acc[mi][ni], 0, 0, 0);
                acc[mi][ni] = __builtin_amdgcn_mfma_f32_16x16x32_bf16(afl[mi], bfh[ni], acc[mi][ni], 0, 0, 0);
            }
    }
    #pragma unroll
    for (int mi = 0; mi < 4; ++mi) {
        int rrow = mi * 16 + ((lane >> 4) << 2);
        #pragma unroll
        for (int ni = 0; ni < 2; ++ni) {
            int c = n0 + ni * 16 + (lane & 15);
            #pragma unroll
            for (int qq = 0; qq < 4; ++qq)
                out[(size_t)(rrow + qq) * 5120 + c] = acc[mi][ni][qq];
        }
    }
}

// ---- fused per-step attention (energy fp16 att_enc; context bf16 enc) ----
__global__ __launch_bounds__(1024) void attn_ctx_kernel(
    const _Float16* __restrict__ att_enc, const float* __restrict__ adg,
    const float* __restrict__ b_dec, const float* __restrict__ Wfull,
    const unsigned short* __restrict__ encb, const float* __restrict__ b_fbeta,
    float* __restrict__ alpha_out, unsigned short* __restrict__ x2h,
    unsigned short* __restrict__ x2l, int t) {
    int b = blockIdx.x; int tid = threadIdx.x;
    __shared__ float sdec[AD], sw[AD], sgate[AD], sal[256], sE[256], red[256];
    __shared__ float sctx[2][AD];
    if (tid < AD) {
        float s = b_dec[tid];
        #pragma unroll
        for (int ks = 0; ks < NSA; ++ks) s += adg[((size_t)ks * BB + b) * 5120 + tid];
        sdec[tid] = s;
        sw[tid] = Wfull[tid];
    } else {
        int e = tid - AD;
        float s = b_fbeta[e];
        #pragma unroll
        for (int ks = 0; ks < NSA; ++ks) s += adg[((size_t)ks * BB + b) * 5120 + 512 + e];
        sgate[e] = s;
    }
    __syncthreads();
    int w = tid >> 6, lane = tid & 63;
    float4 sd0 = *(const float4*)&sdec[lane * 8];
    float4 sd1 = *(const float4*)&sdec[lane * 8 + 4];
    float4 sw0 = *(const float4*)&sw[lane * 8];
    float4 sw1 = *(const float4*)&sw[lane * 8 + 4];
    for (int p = w; p < PP; p += 16) {
        const _Float16* row = att_enc + ((size_t)b * PP + p) * AD + lane * 8;
        h16x8 hv = *(const h16x8*)row;
        float part = fmaxf((float)hv[0] + sd0.x, 0.f) * sw0.x +
                     fmaxf((float)hv[1] + sd0.y, 0.f) * sw0.y +
                     fmaxf((float)hv[2] + sd0.z, 0.f) * sw0.z +
                     fmaxf((float)hv[3] + sd0.w, 0.f) * sw0.w +
                     fmaxf((float)hv[4] + sd1.x, 0.f) * sw1.x +
                     fmaxf((float)hv[5] + sd1.y, 0.f) * sw1.y +
                     fmaxf((float)hv[6] + sd1.z, 0.f) * sw1.z +
                     fmaxf((float)hv[7] + sd1.w, 0.f) * sw1.w;
        #pragma unroll
        for (int off = 32; off > 0; off >>= 1) part += __shfl_down(part, off, 64);
        if (lane == 0) sE[p] = part;
    }
    __syncthreads();
    float myE = (tid < PP) ? sE[tid] : -1e30f;
    if (tid < 256) red[tid] = myE;
    __syncthreads();
    for (int s = 128; s > 0; s >>= 1) {
        if (tid < s) red[tid] = fmaxf(red[tid], red[tid + s]);
        __syncthreads();
    }
    float mx = red[0];
    __syncthreads();
    float ex = (tid < PP) ? __expf(myE - mx) : 0.f;
    if (tid < 256) red[tid] = ex;
    __syncthreads();
    for (int s = 128; s > 0; s >>= 1) {
        if (tid < s) red[tid] += red[tid + s];
        __syncthreads();
    }
    if (tid < PP) {
        float al = ex * (1.f / red[0]);
        sal[tid] = al;
        alpha_out[((size_t)b * TT + t) * PP + tid] = al;
    }
    __syncthreads();
    int e = tid & 511, half = tid >> 9;
    const unsigned short* basep = encb + (size_t)b * PP * ENCD + e;
    float s2 = 0.f;
    #pragma unroll 2
    for (int p = half * 98; p < half * 98 + 98; ++p)
        s2 += sal[p] * bf2f(basep[(size_t)p * ENCD]);
    sctx[half][e] = s2;
    __syncthreads();
    if (tid < AD) {
        float ctx = sctx[0][tid] + sctx[1][tid];
        float gate = sigf(sgate[tid]);
        unsigned short h, l; split2(gate * ctx, h, l);
        size_t o = ((size_t)(tid >> 3) * 64 + b) * 8 + (tid & 7);
        x2h[o] = h; x2l[o] = l;
    }
}

// ---- phase-3: gates -> LSTM; h to axh (bf16 hi/lo) AND hfc (fp16 hi/lo, final GEMM) ----
__global__ __launch_bounds__(256) void gates_lstm2(
    const unsigned short* __restrict__ Ah, const unsigned short* __restrict__ Al,
    const unsigned short* __restrict__ Bh, const unsigned short* __restrict__ Bl,
    const float* __restrict__ pregates, const float* __restrict__ adg,
    float* __restrict__ c, unsigned short* __restrict__ ho_h,
    unsigned short* __restrict__ ho_l, _Float16* __restrict__ hfc_h,
    _Float16* __restrict__ hfc_l, int t) {
    __shared__ float gl[4][64][33];
    int tid = threadIdx.x, lane = tid & 63, w = tid >> 6;
    int n0 = blockIdx.x * 32;
    f32x4 acc[4][2];
    #pragma unroll
    for (int i = 0; i < 4; ++i)
        #pragma unroll
        for (int j = 0; j < 2; ++j) acc[i][j] = (f32x4){0.f, 0.f, 0.f, 0.f};
    #pragma unroll
    for (int s = 0; s < 4; ++s) {
        int kc = w * 16 + s * 4 + (lane >> 4);
        short8 afh[4], afl[4], bfh[2], bfl[2];
        #pragma unroll
        for (int mi = 0; mi < 4; ++mi) {
            size_t o = ((size_t)kc * 64 + mi * 16 + (lane & 15)) * 8;
            afh[mi] = *(const short8*)(Ah + o);
            afl[mi] = *(const short8*)(Al + o);
        }
        #pragma unroll
        for (int ni = 0; ni < 2; ++ni) {
            size_t o = ((size_t)kc * 4096 + n0 + ni * 16 + (lane & 15)) * 8;
            bfh[ni] = *(const short8*)(Bh + o);
            bfl[ni] = *(const short8*)(Bl + o);
        }
        #pragma unroll
        for (int mi = 0; mi < 4; ++mi)
            #pragma unroll
            for (int ni = 0; ni < 2; ++ni) {
                acc[mi][ni] = __builtin_amdgcn_mfma_f32_16x16x32_bf16(afh[mi], bfh[ni], acc[mi][ni], 0, 0, 0);
                acc[mi][ni] = __builtin_amdgcn_mfma_f32_16x16x32_bf16(afh[mi], bfl[ni], acc[mi][ni], 0, 0, 0);
                acc[mi][ni] = __builtin_amdgcn_mfma_f32_16x16x32_bf16(afl[mi], bfh[ni], acc[mi][ni], 0, 0, 0);
            }
    }
    #pragma unroll
    for (int mi = 0; mi < 4; ++mi) {
        int rrow = mi * 16 + ((lane >> 4) << 2);
        #pragma unroll
        for (int ni = 0; ni < 2; ++ni) {
            int cl = ni * 16 + (lane & 15);
            #pragma unroll
            for (int qq = 0; qq < 4; ++qq)
                gl[w][rrow + qq][cl] = acc[mi][ni][qq];
        }
    }
    __syncthreads();
    #pragma unroll
    for (int i = 0; i < 2; ++i) {
        int idx = tid + i * 256;
        int b = idx >> 3, jl = idx & 7;
        float g4[4];
        #pragma unroll
        for (int qq = 0; qq < 4; ++qq)
            g4[qq] = gl[0][b][4 * jl + qq] + gl[1][b][4 * jl + qq] +
                     gl[2][b][4 * jl + qq] + gl[3][b][4 * jl + qq];
        {
            float4 pv = *(const float4*)&pregates[((size_t)(t * 64 + b)) * 4096 + n0 + 4 * jl];
            g4[0] += pv.x; g4[1] += pv.y; g4[2] += pv.z; g4[3] += pv.w;
        }
        #pragma unroll
        for (int ks = 0; ks < NSA; ++ks) {
            float4 av = *(const float4*)&adg[((size_t)ks * BB + b) * 5120 + 1024 + n0 + 4 * jl];
            g4[0] += av.x; g4[1] += av.y; g4[2] += av.z; g4[3] += av.w;
        }
        int j = (n0 >> 2) + jl;
        float cn = sigf(g4[1]) * c[b * HD + j] + sigf(g4[0]) * tanhf(g4[2]);
        c[b * HD + j] = cn;
        float hn = sigf(g4[3]) * tanhf(cn);
        unsigned short h, l; split2(hn, h, l);
        size_t o1 = ((size_t)(j >> 3) * 64 + b) * 8 + (j & 7);
        ho_h[o1] = h; ho_l[o1] = l;
        _Float16 fh, fl; split2h(hn, fh, fl);
        size_t o2 = ((size_t)(j >> 3) * (TT * BB) + b * TT + t) * 8 + (j & 7);
        hfc_h[o2] = fh; hfc_l[o2] = fl;
    }
}

extern "C" void kernel_launch(void* const* d_in, const int* in_sizes, int n_in,
                              void* d_out, int out_size, void* d_ws, size_t ws_size,
                              hipStream_t stream) {
    const float* enc      = (const float*)d_in[0];
    const int*   captions = (const int*)d_in[1];
    const float* W_enc    = (const float*)d_in[3];
    const float* b_enc    = (const float*)d_in[4];
    const float* W_dec    = (const float*)d_in[5];
    const float* b_dec    = (const float*)d_in[6];
    const float* W_full   = (const float*)d_in[7];
    const float* table    = (const float*)d_in[9];
    const float* W_ih     = (const float*)d_in[10];   // [1536][4096]
    const float* b_ih     = (const float*)d_in[11];
    const float* W_hh     = (const float*)d_in[12];   // [1024][4096]
    const float* b_hh     = (const float*)d_in[13];
    const float* W_init_h = (const float*)d_in[14];
    const float* b_init_h = (const float*)d_in[15];
    const float* W_init_c = (const float*)d_in[16];
    const float* b_init_c = (const float*)d_in[17];
    const float* W_fbeta  = (const float*)d_in[18];
    const float* b_fbeta  = (const float*)d_in[19];
    const float* W_fc     = (const float*)d_in[20];
    const float* b_fc     = (const float*)d_in[21];

    float* preds  = (float*)d_out;                         // [64][24][20000]
    float* alphas = (float*)d_out + (size_t)BB * TT * VD;  // [64][24][196]

    // ---- workspace carve. Front region dead after loop -> wfc overlays.
    //      encb aliases wih1 (dead after pregates GEMM). embc/adg share scratch0. ----
    char* base = (char*)d_ws;
    size_t off = 0;
    auto take = [&](size_t b) { void* r = (void*)(base + off); off += (b + 255) & ~(size_t)255; return r; };
    _Float16* att_enc = (_Float16*)take((size_t)12544 * 512 * 2);                // 12.9 MB (fp16)
    unsigned short* wbig_h = (unsigned short*)take((size_t)128 * 5120 * 8 * 2);  // 10.5 x2
    unsigned short* wbig_l = (unsigned short*)take((size_t)128 * 5120 * 8 * 2);
    unsigned short* wih1_h = (unsigned short*)take((size_t)128 * 4096 * 8 * 2);  // 8.4 x2
    unsigned short* wih1_l = (unsigned short*)take((size_t)128 * 4096 * 8 * 2);
    unsigned short* encb   = (unsigned short*)wih1_h;   // 12.85 MB <= 16.8 MB, written after pregates GEMM
    unsigned short* wih2_h = (unsigned short*)take((size_t)64 * 4096 * 8 * 2);   // 4.2 x2
    unsigned short* wih2_l = (unsigned short*)take((size_t)64 * 4096 * 8 * 2);
    unsigned short* wenc_h = (unsigned short*)take((size_t)64 * 512 * 8 * 2);    // 0.52 x2
    unsigned short* wenc_l = (unsigned short*)take((size_t)64 * 512 * 8 * 2);
    float* pregates = (float*)take((size_t)TT * BB * 4096 * 4);                  // 25.2
    float* scratch0 = (float*)take((size_t)TT * BB * ED * 4);                    // 6.3 (embc / adg union)
    unsigned short* embc_h = (unsigned short*)scratch0;                          // 3.15
    unsigned short* embc_l = embc_h + (size_t)128 * TT * BB * 8;                 // 3.15
    float* adg      = scratch0;   // NSA*64*5120*4 = 5.24 MB <= 6.3 MB (embc dead after pregates GEMM)
    float* biasp    = (float*)take((size_t)4096 * 4);
    // wfc (single fp16, 41.2 MB) overlays [0, off): written AFTER the loop
    _Float16* wfc_q = (_Float16*)(base);
    // persistent (live across wfc write):
    float* c_buf = (float*)take((size_t)BB * HD * 4);
    float* mf    = (float*)take((size_t)BB * ENCD * 4);
    unsigned short* axh_h0 = (unsigned short*)take((size_t)192 * 64 * 8 * 2);
    unsigned short* axh_l0 = (unsigned short*)take((size_t)192 * 64 * 8 * 2);
    unsigned short* axh_h1 = (unsigned short*)take((size_t)192 * 64 * 8 * 2);
    unsigned short* axh_l1 = (unsigned short*)take((size_t)192 * 64 * 8 * 2);
    _Float16* hfc_h  = (_Float16*)take((size_t)128 * TT * BB * 8 * 2);           // 3.15 x2
    _Float16* hfc_l  = (_Float16*)take((size_t)128 * TT * BB * 8 * 2);

    // ---- prologue ----
    megasplit_kernel<<<7312, 256, 0, stream>>>(
        W_enc, wenc_h, wenc_l, W_dec, W_fbeta, W_hh, wbig_h, wbig_l,
        W_ih, wih1_h, wih1_l, wih2_h, wih2_l,
        b_ih, b_hh, biasp, captions, table, embc_h, embc_l);
    mean_kernel<<<BB, 512, 0, stream>>>(enc, mf);
    init_hc_kernel<<<dim3(BB, 2), 256, 0, stream>>>(mf, W_init_h, b_init_h, W_init_c, b_init_c,
                                                    axh_h0 + HOFF, axh_l0 + HOFF, c_buf);
    // att_enc(fp16) = enc @ W_enc + b_enc : M=12544 N=512 K=512
    mfma_gemm_bigf<<<392, 256, 0, stream>>>(enc, wenc_h, wenc_l, b_enc, (float*)att_enc,
                                            512, 512, 512, 98, 4, 0, 1);
    // pregates = emb(chunked) @ W_ih[0:1024](perm) + biasp : M=1536 N=4096 K=1024
    mfma_gemm_bigp<<<384, 256, 0, stream>>>(embc_h, embc_l, wih1_h, wih1_l, biasp, pregates,
                                            TT * BB, 4096, 4096, 1024, 12, 32, 1);
    // enc -> bf16 (context operand); aliases wih1 which is now dead
    enc2bf16_kernel<<<3136, 256, 0, stream>>>(enc, encb);

    // ---- step loop: 3 dispatches/step ----
    {
        unsigned short* ah[2] = {axh_h0, axh_h1};
        unsigned short* al[2] = {axh_l0, axh_l1};
        for (int t = 0; t < TT; ++t) {
            int par = t & 1;
            hgemm_direct<<<dim3(40, NSA), 256, 0, stream>>>(
                ah[par] + HOFF, al[par] + HOFF, wbig_h, wbig_l, adg);
            attn_ctx_kernel<<<BB, 1024, 0, stream>>>(att_enc, adg, b_dec, W_full, encb,
                                                     b_fbeta, alphas, ah[par], al[par], t);
            gates_lstm2<<<128, 256, 0, stream>>>(
                ah[par], al[par], wih2_h, wih2_l, pregates, adg, c_buf,
                ah[1 - par] + HOFF, al[1 - par] + HOFF, hfc_h, hfc_l, t);
        }
    }

    // ---- epilogue: wfc split (single fp16) into aliased region; 2-pass fp16 GEMM ----
    split_w_fp16_kernel<<<dim3(79, 128), 256, 0, stream>>>(W_fc, wfc_q, VD, VPAD, VPAD);
    mfma_gemm_fp16<<<1884, 256, 0, stream>>>(hfc_h, hfc_l, wfc_q, b_fc, preds,
                                             TT * BB, VD, VPAD, 1024, 12, 157);
}